// Round 12
// baseline (512.068 us; speedup 1.0000x reference)
//
#include <hip/hip_runtime.h>
#include <math.h>

typedef unsigned short u16;
typedef unsigned int   u32;
typedef __attribute__((ext_vector_type(2))) _Float16 half2_t;

#define B_   32
#define S_   200
#define D_   128
#define T_   199
#define NEGV (-1e30f)

__device__ __forceinline__ float bf2f(u16 u){
  union { u32 i; float f; } v; v.i = ((u32)u) << 16; return v.f;
}
__device__ __forceinline__ u16 f2bf(float f){
  union { float f; u32 i; } v; v.f = f;
  u32 x = v.i;
  return (u16)((x + 0x7fffu + ((x >> 16) & 1u)) >> 16);   // RNE
}
__device__ __forceinline__ u16 f2h(float x){
  union { _Float16 h; u16 u; } v; v.h = (_Float16)x; return v.u;
}
__device__ __forceinline__ float h2f(u16 u){
  union { u16 u; _Float16 h; } v; v.u = u; return (float)v.h;
}
__device__ __forceinline__ u32 pkh(float lo, float hi){
  return ((u32)f2h(hi) << 16) | f2h(lo);
}
// 2 MACs/instr: f32 += f16x2 . f16x2  (v_dot2_f32_f16)
__device__ __forceinline__ float dot2f(u32 w, u32 h, float acc){
#if __has_builtin(__builtin_amdgcn_fdot2)
  union { u32 u; half2_t h2; } a, b;
  a.u = w; b.u = h;
  return __builtin_amdgcn_fdot2(a.h2, b.h2, acc, false);
#else
  union { u32 u; _Float16 f[2]; } a, b;
  a.u = w; b.u = h;
  acc = fmaf((float)a.f[0], (float)b.f[0], acc);
  return fmaf((float)a.f[1], (float)b.f[1], acc);
#endif
}
__device__ __forceinline__ float fast_sigmoid(float x){ return 1.f/(1.f+__expf(-x)); }
__device__ __forceinline__ float fast_tanh(float x){
  float e = __expf(2.f*x);
  return 1.f - 2.f/(e + 1.f);
}

// Raw barrier: drains LDS ops only, NOT vmcnt. __syncthreads would force
// s_waitcnt vmcnt(0) and kill the cross-step global prefetch / store overlap.
#define BARX() asm volatile("s_waitcnt lgkmcnt(0)\n\ts_barrier" ::: "memory")

// Keep a loaded value opaque (no rematerialization across the asm).
#define PINV(x) asm volatile("" : "+v"(x))

// bool storage modes: 0=int32, 1=u8, 2=bf16, 3=f32
__device__ __forceinline__ int readBool(const void* p, int i, int m){
  if (m == 0) return ((const int*)p)[i] != 0;
  if (m == 1) return ((const unsigned char*)p)[i] != 0;
  if (m == 2) return ((const u16*)p)[i] != 0;
  return ((const u32*)p)[i] != 0;
}

__device__ __forceinline__ float dot128f(const float* __restrict__ w,
                                         const float* __restrict__ x){
  float acc = 0.f;
  const float4* wp = (const float4*)w;
  #pragma unroll 8
  for (int i = 0; i < 32; i++){
    float4 v = wp[i]; int k = 4*i;
    acc = fmaf(v.x, x[k],   acc);
    acc = fmaf(v.y, x[k+1], acc);
    acc = fmaf(v.z, x[k+2], acc);
    acc = fmaf(v.w, x[k+3], acc);
  }
  return acc;
}

// ---------------------------------------------------------------- sniffer
__global__ void k_sniff2(const u16* __restrict__ embq_raw,
                         const unsigned char* __restrict__ mask_raw,
                         int* __restrict__ flags){
  __shared__ int bad, gt1, m4, b0;
  const int tid = threadIdx.x;
  if (tid == 0){ bad = 0; gt1 = 0; m4 = 0; b0 = 0; }
  __syncthreads();
  for (int i = tid; i < 512; i += 256){
    u16 u = embq_raw[i];
    if (u){ int e = (u >> 7) & 0xFF; if (e < 0x58 || e > 0x7F) atomicAdd(&bad, 1); }
  }
  for (int i = tid; i < 1024; i += 256){
    unsigned char c = mask_raw[i];
    if (c > 1) atomicAdd(&gt1, 1);
    if (c && (i & 3)) atomicAdd(&m4, 1);
    if (c && !(i & 3)) atomicAdd(&b0, 1);
  }
  __syncthreads();
  if (tid == 0){
    flags[0] = (bad >= 16) ? 1 : 0;
    flags[1] = gt1 ? (b0 ? 2 : 3) : (m4 ? 1 : 0);
  }
}

// ---------------------------------------------------------------- convert floats -> f32
#define NCVT 23
struct CvtArgs { const void* s[NCVT]; int off[NCVT+1]; int nreal[NCVT]; };

__global__ void k_cvt(CvtArgs a, const int* __restrict__ flags, float* __restrict__ dst){
  __shared__ int f;
  if (threadIdx.x == 0) f = flags[0];
  __syncthreads();
  int gid = blockIdx.x * 256 + threadIdx.x;
  if (gid >= a.off[NCVT]) return;
  int ai = 0;
  for (int i = 1; i < NCVT; i++) if (gid >= a.off[i]) ai = i;
  int i = gid - a.off[ai];
  float v = 0.f;
  if (i < a.nreal[ai])
    v = f ? ((const float*)a.s[ai])[i] : bf2f(((const u16*)a.s[ai])[i]);
  dst[gid] = v;
}

// ---------------------------------------------------------------- prep
__global__ void k_prep(const float* __restrict__ WHH1, const float* __restrict__ WHH2,
                       const float* __restrict__ AW,   const float* __restrict__ ALW,
                       const float* __restrict__ WIH1, const float* __restrict__ WIH2,
                       const float* __restrict__ QW,
                       u16* __restrict__ WHH1h, u16* __restrict__ WHH2h,
                       u16* __restrict__ WIH2h,
                       u32* __restrict__ AWt,   u32* __restrict__ ALWt,
                       u32* __restrict__ WIH1t, float* __restrict__ QWt)
{
  const int gid0 = blockIdx.x*256 + threadIdx.x;
  const int stride = gridDim.x*256;
  for (int g = gid0; g < 49152; g += stride){
    WHH1h[g] = f2h(WHH1[g]);
    WHH2h[g] = f2h(WHH2[g]);
    WIH2h[g] = f2h(WIH2[g]);
  }
  // AW: 3 stages of 128x128 -> 8192 u32/stage
  for (int g = gid0; g < 24576; g += stride){
    int s = g >> 13, w = g & 8191;
    int k8 = w >> 9, r = w & 511, c = r >> 2, j = r & 3;
    const float* b = AW + s*16384 + c*128 + k8*8 + 2*j;
    AWt[g] = pkh(b[0], b[1]);
  }
  // ALW: 128x128
  for (int g = gid0; g < 8192; g += stride){
    int k8 = g >> 9, r = g & 511, c = r >> 2, j = r & 3;
    const float* b = ALW + c*128 + k8*8 + 2*j;
    ALWt[g] = pkh(b[0], b[1]);
  }
  // WIH1: 384x256 -> 32 groups x 1536
  for (int g = gid0; g < 49152; g += stride){
    int k8 = g / 1536, r = g % 1536, c = r >> 2, j = r & 3;
    const float* b = WIH1 + c*256 + k8*8 + 2*j;
    WIH1t[g] = pkh(b[0], b[1]);
  }
  // QW: 128x128 f32 -> float4 column layout (32 groups of 4 k)
  for (int g = gid0; g < 16384; g += stride){
    int k4 = g >> 9, r = g & 511, c = r >> 2, j = r & 3;
    QWt[g] = QW[c*128 + k4*4 + j];
  }
}

// ---------------------------------------------------------------- K1: hop aggregation (f16 dot2, coalesced Wt)
template<int ROWS>
__device__ __forceinline__ void agg_stage_h(const u16* __restrict__ tmph,
    const u32* __restrict__ Wt, const float* __restrict__ bg,
    u16* __restrict__ outh, int c)
{
  float bias = bg[c];
  float acc[ROWS];
  #pragma unroll
  for (int r = 0; r < ROWS; r++) acc[r] = bias;
  const uint4* wp = (const uint4*)Wt;
  if constexpr (ROWS <= 4){
    float acc2[ROWS];
    #pragma unroll
    for (int r = 0; r < ROWS; r++) acc2[r] = 0.f;
    #pragma unroll 4
    for (int g = 0; g < 16; g++){
      uint4 wv = wp[g*128 + c];          // coalesced: lanes consecutive
      #pragma unroll
      for (int r = 0; r < ROWS; r++){
        uint4 hv = *(const uint4*)(tmph + r*128 + g*8);   // LDS broadcast
        acc[r]  = dot2f(wv.x, hv.x, acc[r]);
        acc2[r] = dot2f(wv.y, hv.y, acc2[r]);
        acc[r]  = dot2f(wv.z, hv.z, acc[r]);
        acc2[r] = dot2f(wv.w, hv.w, acc2[r]);
      }
    }
    #pragma unroll
    for (int r = 0; r < ROWS; r++)
      outh[r*128 + c] = f2h(fast_tanh(acc[r] + acc2[r]));
  } else {
    #pragma unroll 4
    for (int g = 0; g < 16; g++){
      uint4 wv = wp[g*128 + c];
      #pragma unroll
      for (int r = 0; r < ROWS; r++){
        uint4 hv = *(const uint4*)(tmph + r*128 + g*8);
        acc[r] = dot2f(wv.x, hv.x, acc[r]);
        acc[r] = dot2f(wv.y, hv.y, acc[r]);
        acc[r] = dot2f(wv.z, hv.z, acc[r]);
        acc[r] = dot2f(wv.w, hv.w, acc[r]);
      }
    }
    #pragma unroll
    for (int r = 0; r < ROWS; r++)
      outh[r*128 + c] = f2h(fast_tanh(acc[r]));
  }
}

__launch_bounds__(256, 4)
__global__ void k_agg(const int* __restrict__ question,
                      const int* __restrict__ q_neighbors,
                      const int* __restrict__ s_neighbors,
                      const float* __restrict__ EQ,
                      const float* __restrict__ EC,
                      const u32* __restrict__ AWt,
                      const float* __restrict__ AB,
                      const u32* __restrict__ ALWt,
                      const float* __restrict__ ALB,
                      const void* __restrict__ maskp,
                      const int* __restrict__ flags,
                      float* __restrict__ EQREC)
{
  __shared__ __align__(16) u16 e0h[2][128];
  __shared__ __align__(16) u16 e1h[2][512];
  __shared__ __align__(16) u16 e2h[2][2048];
  __shared__ __align__(16) u16 tmph[2][2048];
  __shared__ int nn1[2][4]; __shared__ int nn2[2][16]; __shared__ int nn3[2][64];
  __shared__ int mskS[2];
  const int tid  = threadIdx.x;
  const int c    = tid & 127;
  const int half = tid >> 7;
  const int bs   = blockIdx.x*2 + half;
  const int n0   = question[bs];
  u16* tp = tmph[half];

  // EQREC[bs] = mask ? agg : EQ[n0]; if BOTH halves are unmasked, the whole
  // aggregation pipeline is dead -> write passthrough and exit (25% of blocks;
  // block-uniform branch, taken before any further barrier).
  if (c == 0) mskS[half] = readBool(maskp, bs, flags[1]);
  __syncthreads();
  const int msk = mskS[half];
  if ((mskS[0] | mskS[1]) == 0){
    EQREC[bs*128 + c] = EQ[n0*128 + c];
    return;
  }

  if (c < 4) nn1[half][c] = q_neighbors[n0*4 + c];
  __syncthreads();
  if (c < 16) nn2[half][c] = s_neighbors[nn1[half][c>>2]*4 + (c&3)];
  __syncthreads();
  if (c < 64) nn3[half][c] = q_neighbors[nn2[half][c>>2]*4 + (c&3)];
  e0h[half][c] = f2h(EQ[n0*128 + c]);
  #pragma unroll
  for (int r = 0; r < 4; r++)  e1h[half][r*128 + c] = f2h(EC[nn1[half][r]*128 + c]);
  #pragma unroll 4
  for (int r = 0; r < 16; r++) e2h[half][r*128 + c] = f2h(EQ[nn2[half][r]*128 + c]);
  __syncthreads();

  auto fill_e0 = [&](){
    float v = 0.25f*(h2f(e1h[half][c]) + h2f(e1h[half][128+c])
                   + h2f(e1h[half][256+c]) + h2f(e1h[half][384+c]))
            + h2f(e0h[half][c]);
    tp[c] = f2h(v);
  };
  auto fill_e1 = [&](){
    #pragma unroll
    for (int r = 0; r < 4; r++){
      float v = 0.25f*(h2f(e2h[half][(4*r)*128+c])   + h2f(e2h[half][(4*r+1)*128+c])
                     + h2f(e2h[half][(4*r+2)*128+c]) + h2f(e2h[half][(4*r+3)*128+c]))
              + h2f(e1h[half][r*128 + c]);
      tp[r*128 + c] = f2h(v);
    }
  };

  // i=0: j=0,1,2
  fill_e0(); __syncthreads();
  agg_stage_h<1>(tp, AWt, AB, e0h[half], c); __syncthreads();
  fill_e1(); __syncthreads();
  agg_stage_h<4>(tp, AWt + 8192, AB + 128, e1h[half], c); __syncthreads();
  #pragma unroll 2
  for (int r = 0; r < 16; r++){
    float m = 0.25f*( EC[nn3[half][4*r]*128+c]   + EC[nn3[half][4*r+1]*128+c]
                    + EC[nn3[half][4*r+2]*128+c] + EC[nn3[half][4*r+3]*128+c] );
    tp[r*128 + c] = f2h(m + h2f(e2h[half][r*128 + c]));
  }
  __syncthreads();
  agg_stage_h<16>(tp, AWt + 16384, AB + 256, e2h[half], c); __syncthreads();
  // i=1: j=0,1
  fill_e0(); __syncthreads();
  agg_stage_h<1>(tp, AWt, AB, e0h[half], c); __syncthreads();
  fill_e1(); __syncthreads();
  agg_stage_h<4>(tp, AWt + 8192, AB + 128, e1h[half], c); __syncthreads();
  // i=2: j=0
  fill_e0(); __syncthreads();
  agg_stage_h<1>(tp, AWt, AB, e0h[half], c); __syncthreads();
  // agg = tanh(e0 @ ALW.T + ALB)
  agg_stage_h<1>(e0h[half], ALWt, ALB, tp, c); __syncthreads();
  EQREC[bs*128 + c] = msk ? h2f(tp[c]) : EQ[n0*128 + c];
}

// ---------------------------------------------------------------- K2: gi1 precompute (K=256, f16 dot2, coalesced)
__launch_bounds__(384, 1)
__global__ void k_gi1(const float* __restrict__ EQREC,
                      const int* __restrict__ response,
                      const float* __restrict__ ECOR,
                      const u32* __restrict__ WIH1t,
                      const float* __restrict__ BIH1,
                      float* __restrict__ GI1)
{
  const int t  = blockIdx.x;
  const int bg = blockIdx.y;
  const int tid = threadIdx.x;
  __shared__ __align__(16) u16 X[8][256];
  for (int o = tid; o < 2048; o += 384){
    int bb = o >> 8, k = o & 255;
    int b = bg*8 + bb;
    float v = (k < 128) ? EQREC[(b*S_ + t)*128 + k]
                        : ECOR[response[b*S_ + t]*128 + (k - 128)];
    X[bb][k] = f2h(v);
  }
  __syncthreads();
  float bias = BIH1[tid];
  float acc[8];
  #pragma unroll
  for (int i = 0; i < 8; i++) acc[i] = bias;
  const uint4* wp = (const uint4*)WIH1t;   // 32 groups x 384
  #pragma unroll 4
  for (int g = 0; g < 32; g++){
    uint4 wv = wp[g*384 + tid];            // coalesced
    #pragma unroll
    for (int bb = 0; bb < 8; bb++){
      uint4 hv = *(const uint4*)(&X[bb][g*8]);   // broadcast
      acc[bb] = dot2f(wv.x, hv.x, acc[bb]);
      acc[bb] = dot2f(wv.y, hv.y, acc[bb]);
      acc[bb] = dot2f(wv.z, hv.z, acc[bb]);
      acc[bb] = dot2f(wv.w, hv.w, acc[bb]);
    }
  }
  #pragma unroll
  for (int bb = 0; bb < 8; bb++)
    GI1[(t*32 + bg*8 + bb)*384 + tid] = acc[bb];
}

// ---------------------------------------------------------------- K4: FUSED h1/h2 recurrence + embedded top-k
// Round-9 structure (2 barriers/step, 4-wave update, topk merged) with ONE
// change: mv()'s h-broadcast now goes through SGPRs instead of 8x uniform
// ds_read_b128 per thread. The wave does ONE ds_read_b32 (lane l -> h-pair
// l&31; consecutive banks, lanes 32-63 broadcast-alias lanes 0-31 = free),
// then v_readlane (SALU pipe, compile-time index) redistributes each pair
// to an SGPR feeding v_dot2_f32_f16 as its one scalar operand. LDS pipe:
// 96 -> 12 wave-reads/step (the measured ~1150cyc/step mv-read cost).
__launch_bounds__(768, 3)
__global__ void k_chain12(const float* __restrict__ GI1,
                          const u16* __restrict__ WHH1h, const float* __restrict__ BHH1,
                          const u16* __restrict__ WIH2h, const float* __restrict__ BIH2,
                          const u16* __restrict__ WHH2h, const float* __restrict__ BHH2,
                          const float* __restrict__ H1I, const float* __restrict__ H2I,
                          float* __restrict__ G2,
                          const int* __restrict__ question,
                          const float* __restrict__ EQ,
                          int* __restrict__ IDX)
{
  const int tid = threadIdx.x;
  __shared__ __align__(16) u16 hh1[128];
  __shared__ __align__(16) u16 hh2[128];
  __shared__ __align__(16) float psBuf[2304];
  __shared__ __align__(16) float qns[12][128];

  if (blockIdx.x >= 32){
    // ---------------- top-k path: 12 waves, one (t,b) pair each; NO block
    // barriers (wave-lockstep + lgkmcnt only).
    const int wv = tid >> 6, lane = tid & 63;
    const int p = (blockIdx.x - 32)*12 + wv;
    if (p >= T_*B_) return;
    const int t = p >> 5, bq = p & 31;
    const int qid = question[bq*S_ + t + 1];
    float* qn = qns[wv];
    qn[lane]      = EQ[qid*128 + lane];
    qn[lane + 64] = EQ[qid*128 + 64 + lane];
    asm volatile("s_waitcnt lgkmcnt(0)" ::: "memory");
    float val[4]; int sv[4];
    #pragma unroll
    for (int i = 0; i < 4; i++){
      int s = lane + 64*i;
      sv[i] = s;
      float v = -3.0e38f;
      if (s < S_) v = (s < t) ? dot128f(EQ + question[bq*S_ + s]*128, qn) : NEGV;
      val[i] = v;
    }
    for (int r = 0; r < 10; r++){
      float bv = -3.0e38f; int bi = 0x3fffffff;
      #pragma unroll
      for (int i = 0; i < 4; i++){
        if (val[i] > bv || (val[i] == bv && sv[i] < bi)){ bv = val[i]; bi = sv[i]; }
      }
      for (int off = 32; off; off >>= 1){
        float ov = __shfl_down(bv, off);
        int   oi = __shfl_down(bi, off);
        if (ov > bv || (ov == bv && oi < bi)){ bv = ov; bi = oi; }
      }
      int win = __shfl(bi, 0);
      if (lane == 0) IDX[p*10 + r] = win;
      #pragma unroll
      for (int i = 0; i < 4; i++) if (sv[i] == win) val[i] = -3.0e38f;
    }
    return;
  }

  // ---------------- chain path (blockIdx 0..31)
  __builtin_amdgcn_s_setprio(1);
  const int b    = blockIdx.x;
  const int lane = tid & 63;

  int half, r0, sidx;
  const u16* wrow;
  const u16* hbase;
  float bias0, bias1, bias2;
  if (tid < 512){
    int i = tid;
    half = (i >= 256) ? 1 : 0; i -= half*256;      // wave-uniform
    r0 = 3*i;                                      // rows r0..r0+2 in [0,768)
    wrow  = ((r0 < 384) ? (WHH1h + r0*128) : (WIH2h + (r0-384)*128)) + half*64;
    hbase = hh1 + half*64;
    sidx  = half*768 + r0;
    if (half == 0){
      if (r0 < 384){ bias0 = BHH1[r0];     bias1 = BHH1[r0+1];   bias2 = BHH1[r0+2]; }
      else         { bias0 = BIH2[r0-384]; bias1 = BIH2[r0-383]; bias2 = BIH2[r0-382]; }
    } else { bias0 = bias1 = bias2 = 0.f; }
  } else {
    int j = tid - 512;
    half = (j >= 128) ? 1 : 0; j -= half*128;      // wave-uniform
    r0 = 3*j;                                      // rows in [0,384)
    wrow  = WHH2h + r0*128 + half*64;
    hbase = hh2 + half*64;
    sidx  = 1536 + half*384 + r0;
    if (half == 0){ bias0 = BHH2[r0]; bias1 = BHH2[r0+1]; bias2 = BHH2[r0+2]; }
    else { bias0 = bias1 = bias2 = 0.f; }
  }
  uint4 Wa[8], Wb[8], Wc[8];
  {
    const uint4* p0 = (const uint4*)(wrow);
    const uint4* p1 = (const uint4*)(wrow + 128);
    const uint4* p2 = (const uint4*)(wrow + 256);
    #pragma unroll
    for (int g = 0; g < 8; g++){ Wa[g] = p0[g]; Wb[g] = p1[g]; Wc[g] = p2[g]; }
  }
  #pragma unroll
  for (int g = 0; g < 8; g++){
    PINV(Wa[g].x); PINV(Wa[g].y); PINV(Wa[g].z); PINV(Wa[g].w);
    PINV(Wb[g].x); PINV(Wb[g].y); PINV(Wb[g].z); PINV(Wb[g].w);
    PINV(Wc[g].x); PINV(Wc[g].y); PINV(Wc[g].z); PINV(Wc[g].w);
  }

  // one b32: lane l -> h-pair (l&31) of this wave's h-half
  const u16* hpair = hbase;   // 64 u16 = 32 u32 pairs

#define DOT3(K, WAC, WBC, WCC) { \
    u32 hk = __builtin_amdgcn_readlane(hreg, (K)); \
    a0 = dot2f(WAC, hk, a0); \
    a1 = dot2f(WBC, hk, a1); \
    a2 = dot2f(WCC, hk, a2); }

  auto mv = [&](){
    u32 hreg = *(const u32*)(hpair + (lane & 31)*2);   // single ds_read_b32
    float a0 = bias0, a1 = bias1, a2 = bias2;
    #pragma unroll
    for (int g = 0; g < 8; g++){
      DOT3(4*g + 0, Wa[g].x, Wb[g].x, Wc[g].x);
      DOT3(4*g + 1, Wa[g].y, Wb[g].y, Wc[g].y);
      DOT3(4*g + 2, Wa[g].z, Wb[g].z, Wc[g].z);
      DOT3(4*g + 3, Wa[g].w, Wb[g].w, Wc[g].w);
    }
    psBuf[sidx] = a0; psBuf[sidx+1] = a1; psBuf[sidx+2] = a2;
  };

  float h1c = 0.f, h2c = 0.f;
  float pc0 = 0.f, pc1 = 0.f, pc2 = 0.f;   // gi1 regs, live in tid [128,256)
  if (tid < 128){
    h2c = H2I[b*128 + tid]; hh2[tid] = f2h(h2c);
  } else if (tid < 256){
    int u = tid - 128;
    h1c = H1I[b*128 + u]; hh1[u] = f2h(h1c);
    const float* gp = GI1 + b*384;         // gi1(0)
    pc0 = gp[u]; pc1 = gp[128+u]; pc2 = gp[256+u];
  }
  BARX();

  // prologue: h1(1) = gru1(x0, h1(0)); C/D partials written here are junk
  // and are overwritten before first read.
  mv();
  BARX();
  if (tid >= 128 && tid < 256){
    int u = tid - 128;
    float r = fast_sigmoid(pc0 + psBuf[u]     + psBuf[768+u]);
    float z = fast_sigmoid(pc1 + psBuf[128+u] + psBuf[896+u]);
    float n = fast_tanh(pc2 + r*(psBuf[256+u] + psBuf[1024+u]));
    h1c = (1.f - z)*n + z*h1c;
    hh1[u] = f2h(h1c);
    const float* gp = GI1 + (32 + b)*384;  // gi1(1)
    pc0 = gp[u]; pc1 = gp[128+u]; pc2 = gp[256+u];
  }
  BARX();

  float* gout = G2 + b*128 + tid;          // dereferenced only for tid<128
  #pragma unroll 1
  for (int t = 0; t < T_; t++){
    // prefetch gi1(t+2) (consumed next iteration; hidden under matvec)
    float pn0 = 0.f, pn1 = 0.f, pn2 = 0.f;
    if (tid >= 128 && tid < 256){
      int u = tid - 128;
      int tp = (t + 2 < T_) ? t + 2 : T_ - 1;
      const float* gp = GI1 + (tp*32 + b)*384;
      pn0 = gp[u]; pn1 = gp[128+u]; pn2 = gp[256+u];
    }
    mv();   // a = WHH1@h1(t+1), c = WIH2@h1(t+1), d = WHH2@h2carry
    BARX();
    if (tid < 128){
      // GRU2: g2(t) = gru2(h1(t+1), h2carry)
      float cs0 = psBuf[384+tid]  + psBuf[1152+tid];
      float cs1 = psBuf[512+tid]  + psBuf[1280+tid];
      float cs2 = psBuf[640+tid]  + psBuf[1408+tid];
      float ds0 = psBuf[1536+tid] + psBuf[1920+tid];
      float ds1 = psBuf[1664+tid] + psBuf[2048+tid];
      float ds2 = psBuf[1792+tid] + psBuf[2176+tid];
      float r2 = fast_sigmoid(cs0 + ds0);
      float z2 = fast_sigmoid(cs1 + ds1);
      float n2 = fast_tanh(cs2 + r2*ds2);
      float g  = (1.f - z2)*n2 + z2*h2c;
      gout[t*4096] = g;                    // G2[(t*32+b)*128+tid]
      if (t > 0) h2c = g;                  // reference: h2 carry frozen at t==0
      hh2[tid] = f2h(h2c);
    } else if (tid < 256){
      // GRU1: h1(t+2) = gru1(x_{t+1}, h1(t+1))
      int u = tid - 128;
      float as0 = psBuf[u]     + psBuf[768+u];
      float as1 = psBuf[128+u] + psBuf[896+u];
      float as2 = psBuf[256+u] + psBuf[1024+u];
      float r1 = fast_sigmoid(pc0 + as0);
      float z1 = fast_sigmoid(pc1 + as1);
      float n1 = fast_tanh(pc2 + r1*as2);
      h1c = (1.f - z1)*n1 + z1*h1c;
      hh1[u] = f2h(h1c);
    }
    pc0 = pn0; pc1 = pn1; pc2 = pn2;
    BARX();
  }
#undef DOT3
}

// ---------------------------------------------------------------- K5: Kp·w_k for all G2 rows (coalesced QWt)
__launch_bounds__(128, 4)
__global__ void k_kp(const float* __restrict__ G2,
                     const float* __restrict__ QWt, const float* __restrict__ QB,
                     const float* __restrict__ MW,
                     float* __restrict__ KPWG)
{
  __shared__ __align__(16) float X[8][128];
  __shared__ float red[8][2];
  const int tid = threadIdx.x;           // c in [0,128)
  const int base = blockIdx.x * 8;       // 796 blocks x 8 rows = 6368
  for (int o = tid; o < 1024; o += 128){
    int r = o >> 7, c = o & 127;
    X[r][c] = G2[(base + r)*128 + c];
  }
  __syncthreads();
  float acc[8];
  float bias = QB[tid];
  #pragma unroll
  for (int r = 0; r < 8; r++) acc[r] = bias;
  const float4* wp = (const float4*)QWt;   // 32 groups x 128
  #pragma unroll 4
  for (int g = 0; g < 32; g++){
    float4 wv = wp[g*128 + tid];           // coalesced
    int kk = 4*g;
    #pragma unroll
    for (int r = 0; r < 8; r++){
      float4 t4 = *(const float4*)(&X[r][kk]);
      acc[r] = fmaf(t4.x, wv.x, acc[r]);
      acc[r] = fmaf(t4.y, wv.y, acc[r]);
      acc[r] = fmaf(t4.z, wv.z, acc[r]);
      acc[r] = fmaf(t4.w, wv.w, acc[r]);
    }
  }
  const float wk = MW[128 + tid];
  const int lane = tid & 63, wv_ = tid >> 6;
  #pragma unroll
  for (int r = 0; r < 8; r++){
    float pv = fast_tanh(acc[r]) * wk;
    for (int off = 32; off; off >>= 1) pv += __shfl_down(pv, off);
    if (lane == 0) red[r][wv_] = pv;
  }
  __syncthreads();
  if (tid < 8) KPWG[base + tid] = red[tid][0] + red[tid][1];
}

// ---------------------------------------------------------------- K6: predict + output
__global__ void k_pred(const int* __restrict__ question,
                       const int* __restrict__ qci, const void* __restrict__ qcm,
                       const int* __restrict__ flags,
                       const float* __restrict__ EQ, const float* __restrict__ EC,
                       const float* __restrict__ QB, const float* __restrict__ MW,
                       const float* __restrict__ G2,
                       const int* __restrict__ IDX,
                       const float* __restrict__ KPWG,
                       void* __restrict__ outp)
{
  const int blk = blockIdx.x;
  const int t = blk >> 5, b = blk & 31;
  const int tid = threadIdx.x;               // 64
  __shared__ float hist[11][132];
  __shared__ float qcs[128];
  __shared__ float og[11];
  __shared__ float kpw[11];
  __shared__ int   idxs[10];
  __shared__ float kpw0s;
  const int qid = question[b*S_ + t + 1];
  const int bflag = flags[1];
  if (tid < 10) idxs[tid] = IDX[blk*10 + tid];
  __syncthreads();
  for (int o = tid; o < 11*128; o += 64){
    int k = o >> 7, c = o & 127;
    float v;
    if (k == 0) v = G2[blk*128 + c];
    else { int s = idxs[k-1]; v = (s == 0) ? 0.f : G2[(s*32 + b)*128 + c]; }
    hist[k][c] = v;
  }
  #pragma unroll
  for (int o = tid; o < 128; o += 64){
    float v = EQ[qid*128 + o];
    #pragma unroll
    for (int q = 0; q < 4; q++){
      if (readBool(qcm, qid*4 + q, bflag))
        v += EC[qci[qid*4 + q]*128 + o];
    }
    qcs[o] = v;
  }
  {
    float pv = fast_tanh(QB[tid])      * MW[128 + tid]
             + fast_tanh(QB[tid + 64]) * MW[128 + tid + 64];
    for (int off = 32; off; off >>= 1) pv += __shfl_down(pv, off);
    if (tid == 0) kpw0s = pv;
  }
  __syncthreads();
  // og[k] = qcs . hist[k], wave-parallel
  #pragma unroll
  for (int k = 0; k < 11; k++){
    float pv = fmaf(qcs[tid], hist[k][tid], qcs[tid+64]*hist[k][tid+64]);
    for (int off = 32; off; off >>= 1) pv += __shfl_down(pv, off);
    if (tid == 0) og[k] = pv;
  }
  if (tid < 11){
    float v;
    if (tid == 0) v = KPWG[blk];
    else { int s = idxs[tid-1]; v = (s == 0) ? kpw0s : KPWG[s*32 + b]; }
    kpw[tid] = v;
  }
  __syncthreads();
  if (tid == 0){
    float tv[11];
    #pragma unroll
    for (int k = 0; k < 11; k++){
      int valid = (k == 0) || (idxs[k-1] < t);
      tv[k] = valid ? kpw[k] : NEGV;
    }
    float m = tv[0];
    #pragma unroll
    for (int k = 1; k < 11; k++) m = fmaxf(m, tv[k]);
    float den = 0.f, num = 0.f;
    #pragma unroll
    for (int k = 0; k < 11; k++){
      float e = __expf(tv[k] - m);
      den += e;
      num = fmaf(e, og[k], num);
    }
    float p = num / den;
    int col = (t == 0) ? 0 : (t + 1);
    if (flags[0]){
      ((float*)outp)[b*S_ + col] = p;
      if (t == 0) ((float*)outp)[b*S_ + 1] = 0.f;
    } else {
      ((u16*)outp)[b*S_ + col] = f2bf(p);
      if (t == 0) ((u16*)outp)[b*S_ + 1] = (u16)0;
    }
  }
}

// ---------------------------------------------------------------- launcher
extern "C" void kernel_launch(void* const* d_in, const int* in_sizes, int n_in,
                              void* d_out, int out_size, void* d_ws, size_t ws_size,
                              hipStream_t stream)
{
  (void)in_sizes; (void)n_in; (void)out_size; (void)ws_size;
  const int* question      = (const int*)d_in[0];
  const int* response      = (const int*)d_in[1];
  const void* maskp        = d_in[2];
  const int* q_neighbors   = (const int*)d_in[3];
  const int* s_neighbors   = (const int*)d_in[4];
  const int* q_concept_idx = (const int*)d_in[5];
  const void* q_concept_mask = d_in[6];

  static const int CN[NCVT] = {2560000,256000,256,98304,49152,384,384,49152,49152,
                               384,384,49152,384,16384,128,16384,128,16384,128,
                               256,1,4096,4096};
  CvtArgs ca;
  int off = 0;
  for (int i = 0; i < NCVT; i++){
    ca.s[i] = d_in[7 + i];
    ca.nreal[i] = CN[i];
    ca.off[i] = off;
    off += (CN[i] + 3) & ~3;
  }
  ca.off[NCVT] = off;
  const int total = off;

  char* ws = (char*)d_ws;
  size_t wo = 0;
  auto alloc = [&](size_t bytes) -> void* {
    void* p = ws + wo;
    wo = (wo + bytes + 255) & ~(size_t)255;
    return p;
  };
  int*   flags = (int*)  alloc(16);
  float* CVT   = (float*)alloc((size_t)total * 4);
  float* EQREC = (float*)alloc((size_t)B_*S_*D_*4);
  float* GI1   = (float*)alloc((size_t)T_*B_*384*4);
  float* G2    = (float*)alloc((size_t)T_*B_*D_*4);
  int*   IDX   = (int*)  alloc((size_t)T_*B_*10*4);
  float* KPWG  = (float*)alloc((size_t)T_*B_*4);
  u16*   WHH1h = (u16*)  alloc(49152*2);
  u16*   WHH2h = (u16*)  alloc(49152*2);
  u16*   WIH2h = (u16*)  alloc(49152*2);
  u32*   AWt   = (u32*)  alloc(24576*4);
  u32*   ALWt  = (u32*)  alloc(8192*4);
  u32*   WIH1t = (u32*)  alloc(49152*4);
  float* QWt   = (float*)alloc(16384*4);

  const float* EQ   = CVT + ca.off[0];
  const float* EC   = CVT + ca.off[1];
  const float* ECOR = CVT + ca.off[2];
  const float* WIH1 = CVT + ca.off[3];
  const float* WHH1 = CVT + ca.off[4];
  const float* BIH1 = CVT + ca.off[5];
  const float* BHH1 = CVT + ca.off[6];
  const float* WIH2 = CVT + ca.off[7];
  const float* WHH2 = CVT + ca.off[8];
  const float* BIH2 = CVT + ca.off[9];
  const float* BHH2 = CVT + ca.off[10];
  const float* AW   = CVT + ca.off[11];
  const float* AB   = CVT + ca.off[12];
  const float* ALW  = CVT + ca.off[13];
  const float* ALB  = CVT + ca.off[14];
  const float* QW   = CVT + ca.off[15];
  const float* QB   = CVT + ca.off[16];
  const float* MW   = CVT + ca.off[19];
  const float* H1I  = CVT + ca.off[21];
  const float* H2I  = CVT + ca.off[22];

  const int TOPK_BLOCKS = (T_*B_ + 11) / 12;   // 531

  k_sniff2<<<1, 256, 0, stream>>>((const u16*)d_in[7], (const unsigned char*)maskp, flags);
  k_cvt<<<(total + 255)/256, 256, 0, stream>>>(ca, flags, CVT);
  k_prep<<<192, 256, 0, stream>>>(WHH1, WHH2, AW, ALW, WIH1, WIH2, QW,
                                  WHH1h, WHH2h, WIH2h, AWt, ALWt, WIH1t, QWt);
  k_agg<<<B_*S_/2, 256, 0, stream>>>(question, q_neighbors, s_neighbors, EQ, EC,
                                     AWt, AB, ALWt, ALB, maskp, flags, EQREC);
  k_gi1<<<dim3(T_, 4), 384, 0, stream>>>(EQREC, response, ECOR, WIH1t, BIH1, GI1);
  k_chain12<<<32 + TOPK_BLOCKS, 768, 0, stream>>>(GI1, WHH1h, BHH1, WIH2h, BIH2,
                                                  WHH2h, BHH2, H1I, H2I, G2,
                                                  question, EQ, IDX);
  k_kp<<<T_*B_/8, 128, 0, stream>>>(G2, QWt, QB, MW, KPWG);
  k_pred<<<T_*B_, 64, 0, stream>>>(question, q_concept_idx, q_concept_mask, flags,
                                   EQ, EC, QB, MW, G2, IDX, KPWG, d_out);
}

// Round 13
// 474.409 us; speedup vs baseline: 1.0794x; 1.0794x over previous
//
#include <hip/hip_runtime.h>
#include <math.h>

typedef unsigned short u16;
typedef unsigned int   u32;
typedef __attribute__((ext_vector_type(2))) _Float16 half2_t;

#define B_   32
#define S_   200
#define D_   128
#define T_   199
#define NEGV (-1e30f)

__device__ __forceinline__ float bf2f(u16 u){
  union { u32 i; float f; } v; v.i = ((u32)u) << 16; return v.f;
}
__device__ __forceinline__ u16 f2bf(float f){
  union { float f; u32 i; } v; v.f = f;
  u32 x = v.i;
  return (u16)((x + 0x7fffu + ((x >> 16) & 1u)) >> 16);   // RNE
}
__device__ __forceinline__ u16 f2h(float x){
  union { _Float16 h; u16 u; } v; v.h = (_Float16)x; return v.u;
}
__device__ __forceinline__ float h2f(u16 u){
  union { u16 u; _Float16 h; } v; v.u = u; return (float)v.h;
}
__device__ __forceinline__ u32 pkh(float lo, float hi){
  return ((u32)f2h(hi) << 16) | f2h(lo);
}
// 2 MACs/instr: f32 += f16x2 . f16x2  (v_dot2_f32_f16)
__device__ __forceinline__ float dot2f(u32 w, u32 h, float acc){
#if __has_builtin(__builtin_amdgcn_fdot2)
  union { u32 u; half2_t h2; } a, b;
  a.u = w; b.u = h;
  return __builtin_amdgcn_fdot2(a.h2, b.h2, acc, false);
#else
  union { u32 u; _Float16 f[2]; } a, b;
  a.u = w; b.u = h;
  acc = fmaf((float)a.f[0], (float)b.f[0], acc);
  return fmaf((float)a.f[1], (float)b.f[1], acc);
#endif
}
__device__ __forceinline__ float fast_sigmoid(float x){ return 1.f/(1.f+__expf(-x)); }
__device__ __forceinline__ float fast_tanh(float x){
  float e = __expf(2.f*x);
  return 1.f - 2.f/(e + 1.f);
}

// Raw barrier: drains LDS ops only, NOT vmcnt. __syncthreads would force
// s_waitcnt vmcnt(0) and kill the cross-step global prefetch / store overlap.
#define BARX() asm volatile("s_waitcnt lgkmcnt(0)\n\ts_barrier" ::: "memory")

// Keep a loaded value opaque (no rematerialization across the asm).
#define PINV(x) asm volatile("" : "+v"(x))

// bool storage modes: 0=int32, 1=u8, 2=bf16, 3=f32
__device__ __forceinline__ int readBool(const void* p, int i, int m){
  if (m == 0) return ((const int*)p)[i] != 0;
  if (m == 1) return ((const unsigned char*)p)[i] != 0;
  if (m == 2) return ((const u16*)p)[i] != 0;
  return ((const u32*)p)[i] != 0;
}

__device__ __forceinline__ float dot128f(const float* __restrict__ w,
                                         const float* __restrict__ x){
  float acc = 0.f;
  const float4* wp = (const float4*)w;
  #pragma unroll 8
  for (int i = 0; i < 32; i++){
    float4 v = wp[i]; int k = 4*i;
    acc = fmaf(v.x, x[k],   acc);
    acc = fmaf(v.y, x[k+1], acc);
    acc = fmaf(v.z, x[k+2], acc);
    acc = fmaf(v.w, x[k+3], acc);
  }
  return acc;
}

// ---------------------------------------------------------------- sniffer
__global__ void k_sniff2(const u16* __restrict__ embq_raw,
                         const unsigned char* __restrict__ mask_raw,
                         int* __restrict__ flags){
  __shared__ int bad, gt1, m4, b0;
  const int tid = threadIdx.x;
  if (tid == 0){ bad = 0; gt1 = 0; m4 = 0; b0 = 0; }
  __syncthreads();
  for (int i = tid; i < 512; i += 256){
    u16 u = embq_raw[i];
    if (u){ int e = (u >> 7) & 0xFF; if (e < 0x58 || e > 0x7F) atomicAdd(&bad, 1); }
  }
  for (int i = tid; i < 1024; i += 256){
    unsigned char c = mask_raw[i];
    if (c > 1) atomicAdd(&gt1, 1);
    if (c && (i & 3)) atomicAdd(&m4, 1);
    if (c && !(i & 3)) atomicAdd(&b0, 1);
  }
  __syncthreads();
  if (tid == 0){
    flags[0] = (bad >= 16) ? 1 : 0;
    flags[1] = gt1 ? (b0 ? 2 : 3) : (m4 ? 1 : 0);
  }
}

// ---------------------------------------------------------------- convert floats -> f32
#define NCVT 23
struct CvtArgs { const void* s[NCVT]; int off[NCVT+1]; int nreal[NCVT]; };

__global__ void k_cvt(CvtArgs a, const int* __restrict__ flags, float* __restrict__ dst){
  __shared__ int f;
  if (threadIdx.x == 0) f = flags[0];
  __syncthreads();
  int gid = blockIdx.x * 256 + threadIdx.x;
  if (gid >= a.off[NCVT]) return;
  int ai = 0;
  for (int i = 1; i < NCVT; i++) if (gid >= a.off[i]) ai = i;
  int i = gid - a.off[ai];
  float v = 0.f;
  if (i < a.nreal[ai])
    v = f ? ((const float*)a.s[ai])[i] : bf2f(((const u16*)a.s[ai])[i]);
  dst[gid] = v;
}

// ---------------------------------------------------------------- prep
__global__ void k_prep(const float* __restrict__ WHH1, const float* __restrict__ WHH2,
                       const float* __restrict__ AW,   const float* __restrict__ ALW,
                       const float* __restrict__ WIH1, const float* __restrict__ WIH2,
                       const float* __restrict__ QW,
                       u16* __restrict__ WHH1h, u16* __restrict__ WHH2h,
                       u16* __restrict__ WIH2h,
                       u32* __restrict__ AWt,   u32* __restrict__ ALWt,
                       u32* __restrict__ WIH1t, float* __restrict__ QWt)
{
  const int gid0 = blockIdx.x*256 + threadIdx.x;
  const int stride = gridDim.x*256;
  for (int g = gid0; g < 49152; g += stride){
    WHH1h[g] = f2h(WHH1[g]);
    WHH2h[g] = f2h(WHH2[g]);
    WIH2h[g] = f2h(WIH2[g]);
  }
  // AW: 3 stages of 128x128 -> 8192 u32/stage
  for (int g = gid0; g < 24576; g += stride){
    int s = g >> 13, w = g & 8191;
    int k8 = w >> 9, r = w & 511, c = r >> 2, j = r & 3;
    const float* b = AW + s*16384 + c*128 + k8*8 + 2*j;
    AWt[g] = pkh(b[0], b[1]);
  }
  // ALW: 128x128
  for (int g = gid0; g < 8192; g += stride){
    int k8 = g >> 9, r = g & 511, c = r >> 2, j = r & 3;
    const float* b = ALW + c*128 + k8*8 + 2*j;
    ALWt[g] = pkh(b[0], b[1]);
  }
  // WIH1: 384x256 -> 32 groups x 1536
  for (int g = gid0; g < 49152; g += stride){
    int k8 = g / 1536, r = g % 1536, c = r >> 2, j = r & 3;
    const float* b = WIH1 + c*256 + k8*8 + 2*j;
    WIH1t[g] = pkh(b[0], b[1]);
  }
  // QW: 128x128 f32 -> float4 column layout (32 groups of 4 k)
  for (int g = gid0; g < 16384; g += stride){
    int k4 = g >> 9, r = g & 511, c = r >> 2, j = r & 3;
    QWt[g] = QW[c*128 + k4*4 + j];
  }
}

// ---------------------------------------------------------------- K1: hop aggregation (f16 dot2, coalesced Wt)
template<int ROWS>
__device__ __forceinline__ void agg_stage_h(const u16* __restrict__ tmph,
    const u32* __restrict__ Wt, const float* __restrict__ bg,
    u16* __restrict__ outh, int c)
{
  float bias = bg[c];
  float acc[ROWS];
  #pragma unroll
  for (int r = 0; r < ROWS; r++) acc[r] = bias;
  const uint4* wp = (const uint4*)Wt;
  if constexpr (ROWS <= 4){
    float acc2[ROWS];
    #pragma unroll
    for (int r = 0; r < ROWS; r++) acc2[r] = 0.f;
    #pragma unroll 4
    for (int g = 0; g < 16; g++){
      uint4 wv = wp[g*128 + c];          // coalesced: lanes consecutive
      #pragma unroll
      for (int r = 0; r < ROWS; r++){
        uint4 hv = *(const uint4*)(tmph + r*128 + g*8);   // LDS broadcast
        acc[r]  = dot2f(wv.x, hv.x, acc[r]);
        acc2[r] = dot2f(wv.y, hv.y, acc2[r]);
        acc[r]  = dot2f(wv.z, hv.z, acc[r]);
        acc2[r] = dot2f(wv.w, hv.w, acc2[r]);
      }
    }
    #pragma unroll
    for (int r = 0; r < ROWS; r++)
      outh[r*128 + c] = f2h(fast_tanh(acc[r] + acc2[r]));
  } else {
    #pragma unroll 4
    for (int g = 0; g < 16; g++){
      uint4 wv = wp[g*128 + c];
      #pragma unroll
      for (int r = 0; r < ROWS; r++){
        uint4 hv = *(const uint4*)(tmph + r*128 + g*8);
        acc[r] = dot2f(wv.x, hv.x, acc[r]);
        acc[r] = dot2f(wv.y, hv.y, acc[r]);
        acc[r] = dot2f(wv.z, hv.z, acc[r]);
        acc[r] = dot2f(wv.w, hv.w, acc[r]);
      }
    }
    #pragma unroll
    for (int r = 0; r < ROWS; r++)
      outh[r*128 + c] = f2h(fast_tanh(acc[r]));
  }
}

__launch_bounds__(256, 4)
__global__ void k_agg(const int* __restrict__ question,
                      const int* __restrict__ q_neighbors,
                      const int* __restrict__ s_neighbors,
                      const float* __restrict__ EQ,
                      const float* __restrict__ EC,
                      const u32* __restrict__ AWt,
                      const float* __restrict__ AB,
                      const u32* __restrict__ ALWt,
                      const float* __restrict__ ALB,
                      const void* __restrict__ maskp,
                      const int* __restrict__ flags,
                      float* __restrict__ EQREC)
{
  __shared__ __align__(16) u16 e0h[2][128];
  __shared__ __align__(16) u16 e1h[2][512];
  __shared__ __align__(16) u16 e2h[2][2048];
  __shared__ __align__(16) u16 tmph[2][2048];
  __shared__ int nn1[2][4]; __shared__ int nn2[2][16]; __shared__ int nn3[2][64];
  __shared__ int mskS[2];
  const int tid  = threadIdx.x;
  const int c    = tid & 127;
  const int half = tid >> 7;
  const int bs   = blockIdx.x*2 + half;
  const int n0   = question[bs];
  u16* tp = tmph[half];

  // EQREC[bs] = mask ? agg : EQ[n0]; if BOTH halves are unmasked, the whole
  // aggregation pipeline is dead -> write passthrough and exit (25% of blocks;
  // block-uniform branch, taken before any further barrier).
  if (c == 0) mskS[half] = readBool(maskp, bs, flags[1]);
  __syncthreads();
  const int msk = mskS[half];
  if ((mskS[0] | mskS[1]) == 0){
    EQREC[bs*128 + c] = EQ[n0*128 + c];
    return;
  }

  if (c < 4) nn1[half][c] = q_neighbors[n0*4 + c];
  __syncthreads();
  if (c < 16) nn2[half][c] = s_neighbors[nn1[half][c>>2]*4 + (c&3)];
  __syncthreads();
  if (c < 64) nn3[half][c] = q_neighbors[nn2[half][c>>2]*4 + (c&3)];
  e0h[half][c] = f2h(EQ[n0*128 + c]);
  #pragma unroll
  for (int r = 0; r < 4; r++)  e1h[half][r*128 + c] = f2h(EC[nn1[half][r]*128 + c]);
  #pragma unroll 4
  for (int r = 0; r < 16; r++) e2h[half][r*128 + c] = f2h(EQ[nn2[half][r]*128 + c]);
  __syncthreads();

  auto fill_e0 = [&](){
    float v = 0.25f*(h2f(e1h[half][c]) + h2f(e1h[half][128+c])
                   + h2f(e1h[half][256+c]) + h2f(e1h[half][384+c]))
            + h2f(e0h[half][c]);
    tp[c] = f2h(v);
  };
  auto fill_e1 = [&](){
    #pragma unroll
    for (int r = 0; r < 4; r++){
      float v = 0.25f*(h2f(e2h[half][(4*r)*128+c])   + h2f(e2h[half][(4*r+1)*128+c])
                     + h2f(e2h[half][(4*r+2)*128+c]) + h2f(e2h[half][(4*r+3)*128+c]))
              + h2f(e1h[half][r*128 + c]);
      tp[r*128 + c] = f2h(v);
    }
  };

  // i=0: j=0,1,2
  fill_e0(); __syncthreads();
  agg_stage_h<1>(tp, AWt, AB, e0h[half], c); __syncthreads();
  fill_e1(); __syncthreads();
  agg_stage_h<4>(tp, AWt + 8192, AB + 128, e1h[half], c); __syncthreads();
  #pragma unroll 2
  for (int r = 0; r < 16; r++){
    float m = 0.25f*( EC[nn3[half][4*r]*128+c]   + EC[nn3[half][4*r+1]*128+c]
                    + EC[nn3[half][4*r+2]*128+c] + EC[nn3[half][4*r+3]*128+c] );
    tp[r*128 + c] = f2h(m + h2f(e2h[half][r*128 + c]));
  }
  __syncthreads();
  agg_stage_h<16>(tp, AWt + 16384, AB + 256, e2h[half], c); __syncthreads();
  // i=1: j=0,1
  fill_e0(); __syncthreads();
  agg_stage_h<1>(tp, AWt, AB, e0h[half], c); __syncthreads();
  fill_e1(); __syncthreads();
  agg_stage_h<4>(tp, AWt + 8192, AB + 128, e1h[half], c); __syncthreads();
  // i=2: j=0
  fill_e0(); __syncthreads();
  agg_stage_h<1>(tp, AWt, AB, e0h[half], c); __syncthreads();
  // agg = tanh(e0 @ ALW.T + ALB)
  agg_stage_h<1>(e0h[half], ALWt, ALB, tp, c); __syncthreads();
  EQREC[bs*128 + c] = msk ? h2f(tp[c]) : EQ[n0*128 + c];
}

// ---------------------------------------------------------------- K2: gi1 precompute (K=256, f16 dot2, coalesced)
__launch_bounds__(384, 1)
__global__ void k_gi1(const float* __restrict__ EQREC,
                      const int* __restrict__ response,
                      const float* __restrict__ ECOR,
                      const u32* __restrict__ WIH1t,
                      const float* __restrict__ BIH1,
                      float* __restrict__ GI1)
{
  const int t  = blockIdx.x;
  const int bg = blockIdx.y;
  const int tid = threadIdx.x;
  __shared__ __align__(16) u16 X[8][256];
  for (int o = tid; o < 2048; o += 384){
    int bb = o >> 8, k = o & 255;
    int b = bg*8 + bb;
    float v = (k < 128) ? EQREC[(b*S_ + t)*128 + k]
                        : ECOR[response[b*S_ + t]*128 + (k - 128)];
    X[bb][k] = f2h(v);
  }
  __syncthreads();
  float bias = BIH1[tid];
  float acc[8];
  #pragma unroll
  for (int i = 0; i < 8; i++) acc[i] = bias;
  const uint4* wp = (const uint4*)WIH1t;   // 32 groups x 384
  #pragma unroll 4
  for (int g = 0; g < 32; g++){
    uint4 wv = wp[g*384 + tid];            // coalesced
    #pragma unroll
    for (int bb = 0; bb < 8; bb++){
      uint4 hv = *(const uint4*)(&X[bb][g*8]);   // broadcast
      acc[bb] = dot2f(wv.x, hv.x, acc[bb]);
      acc[bb] = dot2f(wv.y, hv.y, acc[bb]);
      acc[bb] = dot2f(wv.z, hv.z, acc[bb]);
      acc[bb] = dot2f(wv.w, hv.w, acc[bb]);
    }
  }
  #pragma unroll
  for (int bb = 0; bb < 8; bb++)
    GI1[(t*32 + bg*8 + bb)*384 + tid] = acc[bb];
}

// ---------------------------------------------------------------- K4: FUSED h1/h2 recurrence + embedded top-k
// BEST-KNOWN configuration (round 9, 473us total; chain12 205us).
// Chain path (blockIdx 0..31): 2 raw barriers/step, non-redundant 4-wave
// update, uniform ds_read_b128 h-broadcast. Three rebalancing attempts
// (DPP quad-combine r6, redundant update r10, readlane broadcast r12)
// each regressed ~+41us: every alternative adds net instruction-issue.
// Topk rides along as blocks 32+ (12 waves, one (t,b) pair each, no block
// barriers). Chain waves take s_setprio(1).
__launch_bounds__(768, 3)
__global__ void k_chain12(const float* __restrict__ GI1,
                          const u16* __restrict__ WHH1h, const float* __restrict__ BHH1,
                          const u16* __restrict__ WIH2h, const float* __restrict__ BIH2,
                          const u16* __restrict__ WHH2h, const float* __restrict__ BHH2,
                          const float* __restrict__ H1I, const float* __restrict__ H2I,
                          float* __restrict__ G2,
                          const int* __restrict__ question,
                          const float* __restrict__ EQ,
                          int* __restrict__ IDX)
{
  const int tid = threadIdx.x;
  __shared__ __align__(16) u16 hh1[128];
  __shared__ __align__(16) u16 hh2[128];
  __shared__ __align__(16) float psBuf[2304];
  __shared__ __align__(16) float qns[12][128];

  if (blockIdx.x >= 32){
    // ---------------- top-k path: 12 waves, one (t,b) pair each; NO block
    // barriers (wave-lockstep + lgkmcnt only).
    const int wv = tid >> 6, lane = tid & 63;
    const int p = (blockIdx.x - 32)*12 + wv;
    if (p >= T_*B_) return;
    const int t = p >> 5, bq = p & 31;
    const int qid = question[bq*S_ + t + 1];
    float* qn = qns[wv];
    qn[lane]      = EQ[qid*128 + lane];
    qn[lane + 64] = EQ[qid*128 + 64 + lane];
    asm volatile("s_waitcnt lgkmcnt(0)" ::: "memory");
    float val[4]; int sv[4];
    #pragma unroll
    for (int i = 0; i < 4; i++){
      int s = lane + 64*i;
      sv[i] = s;
      float v = -3.0e38f;
      if (s < S_) v = (s < t) ? dot128f(EQ + question[bq*S_ + s]*128, qn) : NEGV;
      val[i] = v;
    }
    for (int r = 0; r < 10; r++){
      float bv = -3.0e38f; int bi = 0x3fffffff;
      #pragma unroll
      for (int i = 0; i < 4; i++){
        if (val[i] > bv || (val[i] == bv && sv[i] < bi)){ bv = val[i]; bi = sv[i]; }
      }
      for (int off = 32; off; off >>= 1){
        float ov = __shfl_down(bv, off);
        int   oi = __shfl_down(bi, off);
        if (ov > bv || (ov == bv && oi < bi)){ bv = ov; bi = oi; }
      }
      int win = __shfl(bi, 0);
      if (lane == 0) IDX[p*10 + r] = win;
      #pragma unroll
      for (int i = 0; i < 4; i++) if (sv[i] == win) val[i] = -3.0e38f;
    }
    return;
  }

  // ---------------- chain path (blockIdx 0..31)
  __builtin_amdgcn_s_setprio(1);
  const int b = blockIdx.x;

  int half, r0, sidx;
  const u16* wrow;
  const u16* hbase;
  float bias0, bias1, bias2;
  if (tid < 512){
    int i = tid;
    half = (i >= 256) ? 1 : 0; i -= half*256;      // wave-uniform
    r0 = 3*i;                                      // rows r0..r0+2 in [0,768)
    wrow  = ((r0 < 384) ? (WHH1h + r0*128) : (WIH2h + (r0-384)*128)) + half*64;
    hbase = hh1 + half*64;
    sidx  = half*768 + r0;
    if (half == 0){
      if (r0 < 384){ bias0 = BHH1[r0];     bias1 = BHH1[r0+1];   bias2 = BHH1[r0+2]; }
      else         { bias0 = BIH2[r0-384]; bias1 = BIH2[r0-383]; bias2 = BIH2[r0-382]; }
    } else { bias0 = bias1 = bias2 = 0.f; }
  } else {
    int j = tid - 512;
    half = (j >= 128) ? 1 : 0; j -= half*128;      // wave-uniform
    r0 = 3*j;                                      // rows in [0,384)
    wrow  = WHH2h + r0*128 + half*64;
    hbase = hh2 + half*64;
    sidx  = 1536 + half*384 + r0;
    if (half == 0){ bias0 = BHH2[r0]; bias1 = BHH2[r0+1]; bias2 = BHH2[r0+2]; }
    else { bias0 = bias1 = bias2 = 0.f; }
  }
  uint4 Wa[8], Wb[8], Wc[8];
  {
    const uint4* p0 = (const uint4*)(wrow);
    const uint4* p1 = (const uint4*)(wrow + 128);
    const uint4* p2 = (const uint4*)(wrow + 256);
    #pragma unroll
    for (int g = 0; g < 8; g++){ Wa[g] = p0[g]; Wb[g] = p1[g]; Wc[g] = p2[g]; }
  }
  #pragma unroll
  for (int g = 0; g < 8; g++){
    PINV(Wa[g].x); PINV(Wa[g].y); PINV(Wa[g].z); PINV(Wa[g].w);
    PINV(Wb[g].x); PINV(Wb[g].y); PINV(Wb[g].z); PINV(Wb[g].w);
    PINV(Wc[g].x); PINV(Wc[g].y); PINV(Wc[g].z); PINV(Wc[g].w);
  }

  auto mv = [&](){
    float a0 = bias0, a1 = bias1, a2 = bias2;
    #pragma unroll
    for (int g = 0; g < 8; g++){
      uint4 hv = *(const uint4*)(hbase + g*8);    // uniform b128 (broadcast)
      a0 = dot2f(Wa[g].x, hv.x, a0); a0 = dot2f(Wa[g].y, hv.y, a0);
      a0 = dot2f(Wa[g].z, hv.z, a0); a0 = dot2f(Wa[g].w, hv.w, a0);
      a1 = dot2f(Wb[g].x, hv.x, a1); a1 = dot2f(Wb[g].y, hv.y, a1);
      a1 = dot2f(Wb[g].z, hv.z, a1); a1 = dot2f(Wb[g].w, hv.w, a1);
      a2 = dot2f(Wc[g].x, hv.x, a2); a2 = dot2f(Wc[g].y, hv.y, a2);
      a2 = dot2f(Wc[g].z, hv.z, a2); a2 = dot2f(Wc[g].w, hv.w, a2);
    }
    psBuf[sidx] = a0; psBuf[sidx+1] = a1; psBuf[sidx+2] = a2;
  };

  float h1c = 0.f, h2c = 0.f;
  float pc0 = 0.f, pc1 = 0.f, pc2 = 0.f;   // gi1 regs, live in tid [128,256)
  if (tid < 128){
    h2c = H2I[b*128 + tid]; hh2[tid] = f2h(h2c);
  } else if (tid < 256){
    int u = tid - 128;
    h1c = H1I[b*128 + u]; hh1[u] = f2h(h1c);
    const float* gp = GI1 + b*384;         // gi1(0)
    pc0 = gp[u]; pc1 = gp[128+u]; pc2 = gp[256+u];
  }
  BARX();

  // prologue: h1(1) = gru1(x0, h1(0)); C/D partials written here are junk
  // and are overwritten before first read.
  mv();
  BARX();
  if (tid >= 128 && tid < 256){
    int u = tid - 128;
    float r = fast_sigmoid(pc0 + psBuf[u]     + psBuf[768+u]);
    float z = fast_sigmoid(pc1 + psBuf[128+u] + psBuf[896+u]);
    float n = fast_tanh(pc2 + r*(psBuf[256+u] + psBuf[1024+u]));
    h1c = (1.f - z)*n + z*h1c;
    hh1[u] = f2h(h1c);
    const float* gp = GI1 + (32 + b)*384;  // gi1(1)
    pc0 = gp[u]; pc1 = gp[128+u]; pc2 = gp[256+u];
  }
  BARX();

  float* gout = G2 + b*128 + tid;          // dereferenced only for tid<128
  #pragma unroll 1
  for (int t = 0; t < T_; t++){
    // prefetch gi1(t+2) (consumed next iteration; hidden under matvec)
    float pn0 = 0.f, pn1 = 0.f, pn2 = 0.f;
    if (tid >= 128 && tid < 256){
      int u = tid - 128;
      int tp = (t + 2 < T_) ? t + 2 : T_ - 1;
      const float* gp = GI1 + (tp*32 + b)*384;
      pn0 = gp[u]; pn1 = gp[128+u]; pn2 = gp[256+u];
    }
    mv();   // a = WHH1@h1(t+1), c = WIH2@h1(t+1), d = WHH2@h2carry
    BARX();
    if (tid < 128){
      // GRU2: g2(t) = gru2(h1(t+1), h2carry)
      float cs0 = psBuf[384+tid]  + psBuf[1152+tid];
      float cs1 = psBuf[512+tid]  + psBuf[1280+tid];
      float cs2 = psBuf[640+tid]  + psBuf[1408+tid];
      float ds0 = psBuf[1536+tid] + psBuf[1920+tid];
      float ds1 = psBuf[1664+tid] + psBuf[2048+tid];
      float ds2 = psBuf[1792+tid] + psBuf[2176+tid];
      float r2 = fast_sigmoid(cs0 + ds0);
      float z2 = fast_sigmoid(cs1 + ds1);
      float n2 = fast_tanh(cs2 + r2*ds2);
      float g  = (1.f - z2)*n2 + z2*h2c;
      gout[t*4096] = g;                    // G2[(t*32+b)*128+tid]
      if (t > 0) h2c = g;                  // reference: h2 carry frozen at t==0
      hh2[tid] = f2h(h2c);
    } else if (tid < 256){
      // GRU1: h1(t+2) = gru1(x_{t+1}, h1(t+1))
      int u = tid - 128;
      float as0 = psBuf[u]     + psBuf[768+u];
      float as1 = psBuf[128+u] + psBuf[896+u];
      float as2 = psBuf[256+u] + psBuf[1024+u];
      float r1 = fast_sigmoid(pc0 + as0);
      float z1 = fast_sigmoid(pc1 + as1);
      float n1 = fast_tanh(pc2 + r1*as2);
      h1c = (1.f - z1)*n1 + z1*h1c;
      hh1[u] = f2h(h1c);
    }
    pc0 = pn0; pc1 = pn1; pc2 = pn2;
    BARX();
  }
}

// ---------------------------------------------------------------- K5: Kp·w_k for all G2 rows (coalesced QWt)
__launch_bounds__(128, 4)
__global__ void k_kp(const float* __restrict__ G2,
                     const float* __restrict__ QWt, const float* __restrict__ QB,
                     const float* __restrict__ MW,
                     float* __restrict__ KPWG)
{
  __shared__ __align__(16) float X[8][128];
  __shared__ float red[8][2];
  const int tid = threadIdx.x;           // c in [0,128)
  const int base = blockIdx.x * 8;       // 796 blocks x 8 rows = 6368
  for (int o = tid; o < 1024; o += 128){
    int r = o >> 7, c = o & 127;
    X[r][c] = G2[(base + r)*128 + c];
  }
  __syncthreads();
  float acc[8];
  float bias = QB[tid];
  #pragma unroll
  for (int r = 0; r < 8; r++) acc[r] = bias;
  const float4* wp = (const float4*)QWt;   // 32 groups x 128
  #pragma unroll 4
  for (int g = 0; g < 32; g++){
    float4 wv = wp[g*128 + tid];           // coalesced
    int kk = 4*g;
    #pragma unroll
    for (int r = 0; r < 8; r++){
      float4 t4 = *(const float4*)(&X[r][kk]);
      acc[r] = fmaf(t4.x, wv.x, acc[r]);
      acc[r] = fmaf(t4.y, wv.y, acc[r]);
      acc[r] = fmaf(t4.z, wv.z, acc[r]);
      acc[r] = fmaf(t4.w, wv.w, acc[r]);
    }
  }
  const float wk = MW[128 + tid];
  const int lane = tid & 63, wv_ = tid >> 6;
  #pragma unroll
  for (int r = 0; r < 8; r++){
    float pv = fast_tanh(acc[r]) * wk;
    for (int off = 32; off; off >>= 1) pv += __shfl_down(pv, off);
    if (lane == 0) red[r][wv_] = pv;
  }
  __syncthreads();
  if (tid < 8) KPWG[base + tid] = red[tid][0] + red[tid][1];
}

// ---------------------------------------------------------------- K6: predict + output
__global__ void k_pred(const int* __restrict__ question,
                       const int* __restrict__ qci, const void* __restrict__ qcm,
                       const int* __restrict__ flags,
                       const float* __restrict__ EQ, const float* __restrict__ EC,
                       const float* __restrict__ QB, const float* __restrict__ MW,
                       const float* __restrict__ G2,
                       const int* __restrict__ IDX,
                       const float* __restrict__ KPWG,
                       void* __restrict__ outp)
{
  const int blk = blockIdx.x;
  const int t = blk >> 5, b = blk & 31;
  const int tid = threadIdx.x;               // 64
  __shared__ float hist[11][132];
  __shared__ float qcs[128];
  __shared__ float og[11];
  __shared__ float kpw[11];
  __shared__ int   idxs[10];
  __shared__ float kpw0s;
  const int qid = question[b*S_ + t + 1];
  const int bflag = flags[1];
  if (tid < 10) idxs[tid] = IDX[blk*10 + tid];
  __syncthreads();
  for (int o = tid; o < 11*128; o += 64){
    int k = o >> 7, c = o & 127;
    float v;
    if (k == 0) v = G2[blk*128 + c];
    else { int s = idxs[k-1]; v = (s == 0) ? 0.f : G2[(s*32 + b)*128 + c]; }
    hist[k][c] = v;
  }
  #pragma unroll
  for (int o = tid; o < 128; o += 64){
    float v = EQ[qid*128 + o];
    #pragma unroll
    for (int q = 0; q < 4; q++){
      if (readBool(qcm, qid*4 + q, bflag))
        v += EC[qci[qid*4 + q]*128 + o];
    }
    qcs[o] = v;
  }
  {
    float pv = fast_tanh(QB[tid])      * MW[128 + tid]
             + fast_tanh(QB[tid + 64]) * MW[128 + tid + 64];
    for (int off = 32; off; off >>= 1) pv += __shfl_down(pv, off);
    if (tid == 0) kpw0s = pv;
  }
  __syncthreads();
  if (tid < 11){
    float acc = 0.f;
    for (int c = 0; c < 128; c++) acc = fmaf(qcs[c], hist[tid][c], acc);
    og[tid] = acc;
    float v;
    if (tid == 0) v = KPWG[blk];
    else { int s = idxs[tid-1]; v = (s == 0) ? kpw0s : KPWG[s*32 + b]; }
    kpw[tid] = v;
  }
  __syncthreads();
  if (tid == 0){
    float tv[11];
    #pragma unroll
    for (int k = 0; k < 11; k++){
      int valid = (k == 0) || (idxs[k-1] < t);
      tv[k] = valid ? kpw[k] : NEGV;
    }
    float m = tv[0];
    #pragma unroll
    for (int k = 1; k < 11; k++) m = fmaxf(m, tv[k]);
    float den = 0.f, num = 0.f;
    #pragma unroll
    for (int k = 0; k < 11; k++){
      float e = __expf(tv[k] - m);
      den += e;
      num = fmaf(e, og[k], num);
    }
    float p = num / den;
    int col = (t == 0) ? 0 : (t + 1);
    if (flags[0]){
      ((float*)outp)[b*S_ + col] = p;
      if (t == 0) ((float*)outp)[b*S_ + 1] = 0.f;
    } else {
      ((u16*)outp)[b*S_ + col] = f2bf(p);
      if (t == 0) ((u16*)outp)[b*S_ + 1] = (u16)0;
    }
  }
}

// ---------------------------------------------------------------- launcher
extern "C" void kernel_launch(void* const* d_in, const int* in_sizes, int n_in,
                              void* d_out, int out_size, void* d_ws, size_t ws_size,
                              hipStream_t stream)
{
  (void)in_sizes; (void)n_in; (void)out_size; (void)ws_size;
  const int* question      = (const int*)d_in[0];
  const int* response      = (const int*)d_in[1];
  const void* maskp        = d_in[2];
  const int* q_neighbors   = (const int*)d_in[3];
  const int* s_neighbors   = (const int*)d_in[4];
  const int* q_concept_idx = (const int*)d_in[5];
  const void* q_concept_mask = d_in[6];

  static const int CN[NCVT] = {2560000,256000,256,98304,49152,384,384,49152,49152,
                               384,384,49152,384,16384,128,16384,128,16384,128,
                               256,1,4096,4096};
  CvtArgs ca;
  int off = 0;
  for (int i = 0; i < NCVT; i++){
    ca.s[i] = d_in[7 + i];
    ca.nreal[i] = CN[i];
    ca.off[i] = off;
    off += (CN[i] + 3) & ~3;
  }
  ca.off[NCVT] = off;
  const int total = off;

  char* ws = (char*)d_ws;
  size_t wo = 0;
  auto alloc = [&](size_t bytes) -> void* {
    void* p = ws + wo;
    wo = (wo + bytes + 255) & ~(size_t)255;
    return p;
  };
  int*   flags = (int*)  alloc(16);
  float* CVT   = (float*)alloc((size_t)total * 4);
  float* EQREC = (float*)alloc((size_t)B_*S_*D_*4);
  float* GI1   = (float*)alloc((size_t)T_*B_*384*4);
  float* G2    = (float*)alloc((size_t)T_*B_*D_*4);
  int*   IDX   = (int*)  alloc((size_t)T_*B_*10*4);
  float* KPWG  = (float*)alloc((size_t)T_*B_*4);
  u16*   WHH1h = (u16*)  alloc(49152*2);
  u16*   WHH2h = (u16*)  alloc(49152*2);
  u16*   WIH2h = (u16*)  alloc(49152*2);
  u32*   AWt   = (u32*)  alloc(24576*4);
  u32*   ALWt  = (u32*)  alloc(8192*4);
  u32*   WIH1t = (u32*)  alloc(49152*4);
  float* QWt   = (float*)alloc(16384*4);

  const float* EQ   = CVT + ca.off[0];
  const float* EC   = CVT + ca.off[1];
  const float* ECOR = CVT + ca.off[2];
  const float* WIH1 = CVT + ca.off[3];
  const float* WHH1 = CVT + ca.off[4];
  const float* BIH1 = CVT + ca.off[5];
  const float* BHH1 = CVT + ca.off[6];
  const float* WIH2 = CVT + ca.off[7];
  const float* WHH2 = CVT + ca.off[8];
  const float* BIH2 = CVT + ca.off[9];
  const float* BHH2 = CVT + ca.off[10];
  const float* AW   = CVT + ca.off[11];
  const float* AB   = CVT + ca.off[12];
  const float* ALW  = CVT + ca.off[13];
  const float* ALB  = CVT + ca.off[14];
  const float* QW   = CVT + ca.off[15];
  const float* QB   = CVT + ca.off[16];
  const float* MW   = CVT + ca.off[19];
  const float* H1I  = CVT + ca.off[21];
  const float* H2I  = CVT + ca.off[22];

  const int TOPK_BLOCKS = (T_*B_ + 11) / 12;   // 531

  k_sniff2<<<1, 256, 0, stream>>>((const u16*)d_in[7], (const unsigned char*)maskp, flags);
  k_cvt<<<(total + 255)/256, 256, 0, stream>>>(ca, flags, CVT);
  k_prep<<<192, 256, 0, stream>>>(WHH1, WHH2, AW, ALW, WIH1, WIH2, QW,
                                  WHH1h, WHH2h, WIH2h, AWt, ALWt, WIH1t, QWt);
  k_agg<<<B_*S_/2, 256, 0, stream>>>(question, q_neighbors, s_neighbors, EQ, EC,
                                     AWt, AB, ALWt, ALB, maskp, flags, EQREC);
  k_gi1<<<dim3(T_, 4), 384, 0, stream>>>(EQREC, response, ECOR, WIH1t, BIH1, GI1);
  k_chain12<<<32 + TOPK_BLOCKS, 768, 0, stream>>>(GI1, WHH1h, BHH1, WIH2h, BIH2,
                                                  WHH2h, BHH2, H1I, H2I, G2,
                                                  question, EQ, IDX);
  k_kp<<<T_*B_/8, 128, 0, stream>>>(G2, QWt, QB, MW, KPWG);
  k_pred<<<T_*B_, 64, 0, stream>>>(question, q_concept_idx, q_concept_mask, flags,
                                   EQ, EC, QB, MW, G2, IDX, KPWG, d_out);
}

// Round 14
// 473.740 us; speedup vs baseline: 1.0809x; 1.0014x over previous
//
#include <hip/hip_runtime.h>
#include <math.h>

typedef unsigned short u16;
typedef unsigned int   u32;
typedef __attribute__((ext_vector_type(2))) _Float16 half2_t;

#define B_   32
#define S_   200
#define D_   128
#define T_   199
#define NEGV (-1e30f)
#define PREPB 192

__device__ __forceinline__ float bf2f(u16 u){
  union { u32 i; float f; } v; v.i = ((u32)u) << 16; return v.f;
}
__device__ __forceinline__ u16 f2bf(float f){
  union { float f; u32 i; } v; v.f = f;
  u32 x = v.i;
  return (u16)((x + 0x7fffu + ((x >> 16) & 1u)) >> 16);   // RNE
}
__device__ __forceinline__ u16 f2h(float x){
  union { _Float16 h; u16 u; } v; v.h = (_Float16)x; return v.u;
}
__device__ __forceinline__ float h2f(u16 u){
  union { u16 u; _Float16 h; } v; v.u = u; return (float)v.h;
}
__device__ __forceinline__ u32 pkh(float lo, float hi){
  return ((u32)f2h(hi) << 16) | f2h(lo);
}
// 2 MACs/instr: f32 += f16x2 . f16x2  (v_dot2_f32_f16)
__device__ __forceinline__ float dot2f(u32 w, u32 h, float acc){
#if __has_builtin(__builtin_amdgcn_fdot2)
  union { u32 u; half2_t h2; } a, b;
  a.u = w; b.u = h;
  return __builtin_amdgcn_fdot2(a.h2, b.h2, acc, false);
#else
  union { u32 u; _Float16 f[2]; } a, b;
  a.u = w; b.u = h;
  acc = fmaf((float)a.f[0], (float)b.f[0], acc);
  return fmaf((float)a.f[1], (float)b.f[1], acc);
#endif
}
__device__ __forceinline__ float fast_sigmoid(float x){ return 1.f/(1.f+__expf(-x)); }
__device__ __forceinline__ float fast_tanh(float x){
  float e = __expf(2.f*x);
  return 1.f - 2.f/(e + 1.f);
}

// Raw barrier: drains LDS ops only, NOT vmcnt. __syncthreads would force
// s_waitcnt vmcnt(0) and kill the cross-step global prefetch / store overlap.
#define BARX() asm volatile("s_waitcnt lgkmcnt(0)\n\ts_barrier" ::: "memory")

// Keep a loaded value opaque (no rematerialization across the asm).
#define PINV(x) asm volatile("" : "+v"(x))

// bool storage modes: 0=int32, 1=u8, 2=bf16, 3=f32
__device__ __forceinline__ int readBool(const void* p, int i, int m){
  if (m == 0) return ((const int*)p)[i] != 0;
  if (m == 1) return ((const unsigned char*)p)[i] != 0;
  if (m == 2) return ((const u16*)p)[i] != 0;
  return ((const u32*)p)[i] != 0;
}

__device__ __forceinline__ float dot128f(const float* __restrict__ w,
                                         const float* __restrict__ x){
  float acc = 0.f;
  const float4* wp = (const float4*)w;
  #pragma unroll 8
  for (int i = 0; i < 32; i++){
    float4 v = wp[i]; int k = 4*i;
    acc = fmaf(v.x, x[k],   acc);
    acc = fmaf(v.y, x[k+1], acc);
    acc = fmaf(v.z, x[k+2], acc);
    acc = fmaf(v.w, x[k+3], acc);
  }
  return acc;
}

// ---------------------------------------------------------------- merged cvt+prep (+sniff)
// Every block recomputes the f32-vs-bf16 flag from the first 512 raw u16 of
// embed_question (1.5KB, L2-broadcast -- no cross-block ordering needed).
// Block 0 also does the mask-mode sniff and publishes flags[] for
// k_agg/k_pred (stream-ordered after this kernel). Prep blocks read RAW
// weight inputs with inline conversion (numerically identical to reading
// the CVT output) so they ride in the same grid as cvt -- kills 2 of the 8
// dispatch boundaries.
#define NCVT 23
struct CvtArgs { const void* s[NCVT]; int off[NCVT+1]; int nreal[NCVT]; };

__global__ void k_cvtprep(CvtArgs a, int nCvtBlk,
                          const u16* __restrict__ embq_raw,
                          const unsigned char* __restrict__ mask_raw,
                          int* __restrict__ flags,
                          const void* __restrict__ rWIH1, const void* __restrict__ rWHH1,
                          const void* __restrict__ rWIH2, const void* __restrict__ rWHH2,
                          const void* __restrict__ rAW,   const void* __restrict__ rALW,
                          const void* __restrict__ rQW,
                          float* __restrict__ dst,
                          u16* __restrict__ WHH1h, u16* __restrict__ WHH2h,
                          u16* __restrict__ WIH2h,
                          u32* __restrict__ AWt,   u32* __restrict__ ALWt,
                          u32* __restrict__ WIH1t, float* __restrict__ QWt)
{
  __shared__ int sbad;
  const int tid = threadIdx.x;
  if (tid == 0) sbad = 0;
  __syncthreads();
  for (int i = tid; i < 512; i += 256){
    u16 u = embq_raw[i];
    if (u){ int e = (u >> 7) & 0xFF; if (e < 0x58 || e > 0x7F) atomicAdd(&sbad, 1); }
  }
  __syncthreads();
  const int f = (sbad >= 16) ? 1 : 0;

  if (blockIdx.x == 0){
    __shared__ int gt1, m4, b0;
    if (tid == 0){ gt1 = 0; m4 = 0; b0 = 0; }
    __syncthreads();
    for (int i = tid; i < 1024; i += 256){
      unsigned char c = mask_raw[i];
      if (c > 1) atomicAdd(&gt1, 1);
      if (c && (i & 3)) atomicAdd(&m4, 1);
      if (c && !(i & 3)) atomicAdd(&b0, 1);
    }
    __syncthreads();
    if (tid == 0){
      flags[0] = f;
      flags[1] = gt1 ? (b0 ? 2 : 3) : (m4 ? 1 : 0);
    }
  }

  if (blockIdx.x < nCvtBlk){
    // ---- cvt role
    int gid = blockIdx.x * 256 + tid;
    if (gid < a.off[NCVT]){
      int ai = 0;
      for (int i = 1; i < NCVT; i++) if (gid >= a.off[i]) ai = i;
      int i = gid - a.off[ai];
      float v = 0.f;
      if (i < a.nreal[ai])
        v = f ? ((const float*)a.s[ai])[i] : bf2f(((const u16*)a.s[ai])[i]);
      dst[gid] = v;
    }
    return;
  }

  // ---- prep role (PREPB blocks), raw-input inline conversion
  auto ldf = [&](const void* p, int i) -> float {
    return f ? ((const float*)p)[i] : bf2f(((const u16*)p)[i]);
  };
  const int gid0 = (blockIdx.x - nCvtBlk)*256 + tid;
  const int stride = PREPB*256;
  for (int g = gid0; g < 49152; g += stride){
    WHH1h[g] = f2h(ldf(rWHH1, g));
    WHH2h[g] = f2h(ldf(rWHH2, g));
    WIH2h[g] = f2h(ldf(rWIH2, g));
  }
  // AW: 3 stages of 128x128 -> 8192 u32/stage
  for (int g = gid0; g < 24576; g += stride){
    int s = g >> 13, w = g & 8191;
    int k8 = w >> 9, r = w & 511, c = r >> 2, j = r & 3;
    int base = s*16384 + c*128 + k8*8 + 2*j;
    AWt[g] = pkh(ldf(rAW, base), ldf(rAW, base + 1));
  }
  // ALW: 128x128
  for (int g = gid0; g < 8192; g += stride){
    int k8 = g >> 9, r = g & 511, c = r >> 2, j = r & 3;
    int base = c*128 + k8*8 + 2*j;
    ALWt[g] = pkh(ldf(rALW, base), ldf(rALW, base + 1));
  }
  // WIH1: 384x256 -> 32 groups x 1536
  for (int g = gid0; g < 49152; g += stride){
    int k8 = g / 1536, r = g % 1536, c = r >> 2, j = r & 3;
    int base = c*256 + k8*8 + 2*j;
    WIH1t[g] = pkh(ldf(rWIH1, base), ldf(rWIH1, base + 1));
  }
  // QW: 128x128 f32 -> float4 column layout (32 groups of 4 k)
  for (int g = gid0; g < 16384; g += stride){
    int k4 = g >> 9, r = g & 511, c = r >> 2, j = r & 3;
    QWt[g] = ldf(rQW, c*128 + k4*4 + j);
  }
}

// ---------------------------------------------------------------- K1: hop aggregation (f16 dot2, coalesced Wt)
template<int ROWS>
__device__ __forceinline__ void agg_stage_h(const u16* __restrict__ tmph,
    const u32* __restrict__ Wt, const float* __restrict__ bg,
    u16* __restrict__ outh, int c)
{
  float bias = bg[c];
  float acc[ROWS];
  #pragma unroll
  for (int r = 0; r < ROWS; r++) acc[r] = bias;
  const uint4* wp = (const uint4*)Wt;
  if constexpr (ROWS <= 4){
    float acc2[ROWS];
    #pragma unroll
    for (int r = 0; r < ROWS; r++) acc2[r] = 0.f;
    #pragma unroll 4
    for (int g = 0; g < 16; g++){
      uint4 wv = wp[g*128 + c];          // coalesced: lanes consecutive
      #pragma unroll
      for (int r = 0; r < ROWS; r++){
        uint4 hv = *(const uint4*)(tmph + r*128 + g*8);   // LDS broadcast
        acc[r]  = dot2f(wv.x, hv.x, acc[r]);
        acc2[r] = dot2f(wv.y, hv.y, acc2[r]);
        acc[r]  = dot2f(wv.z, hv.z, acc[r]);
        acc2[r] = dot2f(wv.w, hv.w, acc2[r]);
      }
    }
    #pragma unroll
    for (int r = 0; r < ROWS; r++)
      outh[r*128 + c] = f2h(fast_tanh(acc[r] + acc2[r]));
  } else {
    #pragma unroll 4
    for (int g = 0; g < 16; g++){
      uint4 wv = wp[g*128 + c];
      #pragma unroll
      for (int r = 0; r < ROWS; r++){
        uint4 hv = *(const uint4*)(tmph + r*128 + g*8);
        acc[r] = dot2f(wv.x, hv.x, acc[r]);
        acc[r] = dot2f(wv.y, hv.y, acc[r]);
        acc[r] = dot2f(wv.z, hv.z, acc[r]);
        acc[r] = dot2f(wv.w, hv.w, acc[r]);
      }
    }
    #pragma unroll
    for (int r = 0; r < ROWS; r++)
      outh[r*128 + c] = f2h(fast_tanh(acc[r]));
  }
}

__launch_bounds__(256, 4)
__global__ void k_agg(const int* __restrict__ question,
                      const int* __restrict__ q_neighbors,
                      const int* __restrict__ s_neighbors,
                      const float* __restrict__ EQ,
                      const float* __restrict__ EC,
                      const u32* __restrict__ AWt,
                      const float* __restrict__ AB,
                      const u32* __restrict__ ALWt,
                      const float* __restrict__ ALB,
                      const void* __restrict__ maskp,
                      const int* __restrict__ flags,
                      float* __restrict__ EQREC)
{
  __shared__ __align__(16) u16 e0h[2][128];
  __shared__ __align__(16) u16 e1h[2][512];
  __shared__ __align__(16) u16 e2h[2][2048];
  __shared__ __align__(16) u16 tmph[2][2048];
  __shared__ int nn1[2][4]; __shared__ int nn2[2][16]; __shared__ int nn3[2][64];
  __shared__ int mskS[2];
  const int tid  = threadIdx.x;
  const int c    = tid & 127;
  const int half = tid >> 7;
  const int bs   = blockIdx.x*2 + half;
  const int n0   = question[bs];
  u16* tp = tmph[half];

  // EQREC[bs] = mask ? agg : EQ[n0]; if BOTH halves are unmasked, the whole
  // aggregation pipeline is dead -> write passthrough and exit (25% of blocks;
  // block-uniform branch, taken before any further barrier).
  if (c == 0) mskS[half] = readBool(maskp, bs, flags[1]);
  __syncthreads();
  const int msk = mskS[half];
  if ((mskS[0] | mskS[1]) == 0){
    EQREC[bs*128 + c] = EQ[n0*128 + c];
    return;
  }

  if (c < 4) nn1[half][c] = q_neighbors[n0*4 + c];
  __syncthreads();
  if (c < 16) nn2[half][c] = s_neighbors[nn1[half][c>>2]*4 + (c&3)];
  __syncthreads();
  if (c < 64) nn3[half][c] = q_neighbors[nn2[half][c>>2]*4 + (c&3)];
  e0h[half][c] = f2h(EQ[n0*128 + c]);
  #pragma unroll
  for (int r = 0; r < 4; r++)  e1h[half][r*128 + c] = f2h(EC[nn1[half][r]*128 + c]);
  #pragma unroll 4
  for (int r = 0; r < 16; r++) e2h[half][r*128 + c] = f2h(EQ[nn2[half][r]*128 + c]);
  __syncthreads();

  auto fill_e0 = [&](){
    float v = 0.25f*(h2f(e1h[half][c]) + h2f(e1h[half][128+c])
                   + h2f(e1h[half][256+c]) + h2f(e1h[half][384+c]))
            + h2f(e0h[half][c]);
    tp[c] = f2h(v);
  };
  auto fill_e1 = [&](){
    #pragma unroll
    for (int r = 0; r < 4; r++){
      float v = 0.25f*(h2f(e2h[half][(4*r)*128+c])   + h2f(e2h[half][(4*r+1)*128+c])
                     + h2f(e2h[half][(4*r+2)*128+c]) + h2f(e2h[half][(4*r+3)*128+c]))
              + h2f(e1h[half][r*128 + c]);
      tp[r*128 + c] = f2h(v);
    }
  };

  // i=0: j=0,1,2
  fill_e0(); __syncthreads();
  agg_stage_h<1>(tp, AWt, AB, e0h[half], c); __syncthreads();
  fill_e1(); __syncthreads();
  agg_stage_h<4>(tp, AWt + 8192, AB + 128, e1h[half], c); __syncthreads();
  #pragma unroll 2
  for (int r = 0; r < 16; r++){
    float m = 0.25f*( EC[nn3[half][4*r]*128+c]   + EC[nn3[half][4*r+1]*128+c]
                    + EC[nn3[half][4*r+2]*128+c] + EC[nn3[half][4*r+3]*128+c] );
    tp[r*128 + c] = f2h(m + h2f(e2h[half][r*128 + c]));
  }
  __syncthreads();
  agg_stage_h<16>(tp, AWt + 16384, AB + 256, e2h[half], c); __syncthreads();
  // i=1: j=0,1
  fill_e0(); __syncthreads();
  agg_stage_h<1>(tp, AWt, AB, e0h[half], c); __syncthreads();
  fill_e1(); __syncthreads();
  agg_stage_h<4>(tp, AWt + 8192, AB + 128, e1h[half], c); __syncthreads();
  // i=2: j=0
  fill_e0(); __syncthreads();
  agg_stage_h<1>(tp, AWt, AB, e0h[half], c); __syncthreads();
  // agg = tanh(e0 @ ALW.T + ALB)
  agg_stage_h<1>(e0h[half], ALWt, ALB, tp, c); __syncthreads();
  EQREC[bs*128 + c] = msk ? h2f(tp[c]) : EQ[n0*128 + c];
}

// ---------------------------------------------------------------- K2: gi1 precompute (K=256, f16 dot2, coalesced)
__launch_bounds__(384, 1)
__global__ void k_gi1(const float* __restrict__ EQREC,
                      const int* __restrict__ response,
                      const float* __restrict__ ECOR,
                      const u32* __restrict__ WIH1t,
                      const float* __restrict__ BIH1,
                      float* __restrict__ GI1)
{
  const int t  = blockIdx.x;
  const int bg = blockIdx.y;
  const int tid = threadIdx.x;
  __shared__ __align__(16) u16 X[8][256];
  for (int o = tid; o < 2048; o += 384){
    int bb = o >> 8, k = o & 255;
    int b = bg*8 + bb;
    float v = (k < 128) ? EQREC[(b*S_ + t)*128 + k]
                        : ECOR[response[b*S_ + t]*128 + (k - 128)];
    X[bb][k] = f2h(v);
  }
  __syncthreads();
  float bias = BIH1[tid];
  float acc[8];
  #pragma unroll
  for (int i = 0; i < 8; i++) acc[i] = bias;
  const uint4* wp = (const uint4*)WIH1t;   // 32 groups x 384
  #pragma unroll 4
  for (int g = 0; g < 32; g++){
    uint4 wv = wp[g*384 + tid];            // coalesced
    #pragma unroll
    for (int bb = 0; bb < 8; bb++){
      uint4 hv = *(const uint4*)(&X[bb][g*8]);   // broadcast
      acc[bb] = dot2f(wv.x, hv.x, acc[bb]);
      acc[bb] = dot2f(wv.y, hv.y, acc[bb]);
      acc[bb] = dot2f(wv.z, hv.z, acc[bb]);
      acc[bb] = dot2f(wv.w, hv.w, acc[bb]);
    }
  }
  #pragma unroll
  for (int bb = 0; bb < 8; bb++)
    GI1[(t*32 + bg*8 + bb)*384 + tid] = acc[bb];
}

// ---------------------------------------------------------------- K4: FUSED h1/h2 recurrence + embedded top-k
// BEST-KNOWN configuration (rounds 9/13, 473-474us total; chain12 205us).
// Chain path (blockIdx 0..31): 2 raw barriers/step, non-redundant 4-wave
// update, uniform ds_read_b128 h-broadcast. Three rebalancing attempts
// (DPP quad-combine r6, redundant update r10, readlane broadcast r12)
// each regressed ~+41us: every alternative adds net instruction-issue.
// Topk rides along as blocks 32+ (12 waves, one (t,b) pair each, no block
// barriers). Chain waves take s_setprio(1).
__launch_bounds__(768, 3)
__global__ void k_chain12(const float* __restrict__ GI1,
                          const u16* __restrict__ WHH1h, const float* __restrict__ BHH1,
                          const u16* __restrict__ WIH2h, const float* __restrict__ BIH2,
                          const u16* __restrict__ WHH2h, const float* __restrict__ BHH2,
                          const float* __restrict__ H1I, const float* __restrict__ H2I,
                          float* __restrict__ G2,
                          const int* __restrict__ question,
                          const float* __restrict__ EQ,
                          int* __restrict__ IDX)
{
  const int tid = threadIdx.x;
  __shared__ __align__(16) u16 hh1[128];
  __shared__ __align__(16) u16 hh2[128];
  __shared__ __align__(16) float psBuf[2304];
  __shared__ __align__(16) float qns[12][128];

  if (blockIdx.x >= 32){
    // ---------------- top-k path: 12 waves, one (t,b) pair each; NO block
    // barriers (wave-lockstep + lgkmcnt only).
    const int wv = tid >> 6, lane = tid & 63;
    const int p = (blockIdx.x - 32)*12 + wv;
    if (p >= T_*B_) return;
    const int t = p >> 5, bq = p & 31;
    const int qid = question[bq*S_ + t + 1];
    float* qn = qns[wv];
    qn[lane]      = EQ[qid*128 + lane];
    qn[lane + 64] = EQ[qid*128 + 64 + lane];
    asm volatile("s_waitcnt lgkmcnt(0)" ::: "memory");
    float val[4]; int sv[4];
    #pragma unroll
    for (int i = 0; i < 4; i++){
      int s = lane + 64*i;
      sv[i] = s;
      float v = -3.0e38f;
      if (s < S_) v = (s < t) ? dot128f(EQ + question[bq*S_ + s]*128, qn) : NEGV;
      val[i] = v;
    }
    for (int r = 0; r < 10; r++){
      float bv = -3.0e38f; int bi = 0x3fffffff;
      #pragma unroll
      for (int i = 0; i < 4; i++){
        if (val[i] > bv || (val[i] == bv && sv[i] < bi)){ bv = val[i]; bi = sv[i]; }
      }
      for (int off = 32; off; off >>= 1){
        float ov = __shfl_down(bv, off);
        int   oi = __shfl_down(bi, off);
        if (ov > bv || (ov == bv && oi < bi)){ bv = ov; bi = oi; }
      }
      int win = __shfl(bi, 0);
      if (lane == 0) IDX[p*10 + r] = win;
      #pragma unroll
      for (int i = 0; i < 4; i++) if (sv[i] == win) val[i] = -3.0e38f;
    }
    return;
  }

  // ---------------- chain path (blockIdx 0..31)
  __builtin_amdgcn_s_setprio(1);
  const int b = blockIdx.x;

  int half, r0, sidx;
  const u16* wrow;
  const u16* hbase;
  float bias0, bias1, bias2;
  if (tid < 512){
    int i = tid;
    half = (i >= 256) ? 1 : 0; i -= half*256;      // wave-uniform
    r0 = 3*i;                                      // rows r0..r0+2 in [0,768)
    wrow  = ((r0 < 384) ? (WHH1h + r0*128) : (WIH2h + (r0-384)*128)) + half*64;
    hbase = hh1 + half*64;
    sidx  = half*768 + r0;
    if (half == 0){
      if (r0 < 384){ bias0 = BHH1[r0];     bias1 = BHH1[r0+1];   bias2 = BHH1[r0+2]; }
      else         { bias0 = BIH2[r0-384]; bias1 = BIH2[r0-383]; bias2 = BIH2[r0-382]; }
    } else { bias0 = bias1 = bias2 = 0.f; }
  } else {
    int j = tid - 512;
    half = (j >= 128) ? 1 : 0; j -= half*128;      // wave-uniform
    r0 = 3*j;                                      // rows in [0,384)
    wrow  = WHH2h + r0*128 + half*64;
    hbase = hh2 + half*64;
    sidx  = 1536 + half*384 + r0;
    if (half == 0){ bias0 = BHH2[r0]; bias1 = BHH2[r0+1]; bias2 = BHH2[r0+2]; }
    else { bias0 = bias1 = bias2 = 0.f; }
  }
  uint4 Wa[8], Wb[8], Wc[8];
  {
    const uint4* p0 = (const uint4*)(wrow);
    const uint4* p1 = (const uint4*)(wrow + 128);
    const uint4* p2 = (const uint4*)(wrow + 256);
    #pragma unroll
    for (int g = 0; g < 8; g++){ Wa[g] = p0[g]; Wb[g] = p1[g]; Wc[g] = p2[g]; }
  }
  #pragma unroll
  for (int g = 0; g < 8; g++){
    PINV(Wa[g].x); PINV(Wa[g].y); PINV(Wa[g].z); PINV(Wa[g].w);
    PINV(Wb[g].x); PINV(Wb[g].y); PINV(Wb[g].z); PINV(Wb[g].w);
    PINV(Wc[g].x); PINV(Wc[g].y); PINV(Wc[g].z); PINV(Wc[g].w);
  }

  auto mv = [&](){
    float a0 = bias0, a1 = bias1, a2 = bias2;
    #pragma unroll
    for (int g = 0; g < 8; g++){
      uint4 hv = *(const uint4*)(hbase + g*8);    // uniform b128 (broadcast)
      a0 = dot2f(Wa[g].x, hv.x, a0); a0 = dot2f(Wa[g].y, hv.y, a0);
      a0 = dot2f(Wa[g].z, hv.z, a0); a0 = dot2f(Wa[g].w, hv.w, a0);
      a1 = dot2f(Wb[g].x, hv.x, a1); a1 = dot2f(Wb[g].y, hv.y, a1);
      a1 = dot2f(Wb[g].z, hv.z, a1); a1 = dot2f(Wb[g].w, hv.w, a1);
      a2 = dot2f(Wc[g].x, hv.x, a2); a2 = dot2f(Wc[g].y, hv.y, a2);
      a2 = dot2f(Wc[g].z, hv.z, a2); a2 = dot2f(Wc[g].w, hv.w, a2);
    }
    psBuf[sidx] = a0; psBuf[sidx+1] = a1; psBuf[sidx+2] = a2;
  };

  float h1c = 0.f, h2c = 0.f;
  float pc0 = 0.f, pc1 = 0.f, pc2 = 0.f;   // gi1 regs, live in tid [128,256)
  if (tid < 128){
    h2c = H2I[b*128 + tid]; hh2[tid] = f2h(h2c);
  } else if (tid < 256){
    int u = tid - 128;
    h1c = H1I[b*128 + u]; hh1[u] = f2h(h1c);
    const float* gp = GI1 + b*384;         // gi1(0)
    pc0 = gp[u]; pc1 = gp[128+u]; pc2 = gp[256+u];
  }
  BARX();

  // prologue: h1(1) = gru1(x0, h1(0)); C/D partials written here are junk
  // and are overwritten before first read.
  mv();
  BARX();
  if (tid >= 128 && tid < 256){
    int u = tid - 128;
    float r = fast_sigmoid(pc0 + psBuf[u]     + psBuf[768+u]);
    float z = fast_sigmoid(pc1 + psBuf[128+u] + psBuf[896+u]);
    float n = fast_tanh(pc2 + r*(psBuf[256+u] + psBuf[1024+u]));
    h1c = (1.f - z)*n + z*h1c;
    hh1[u] = f2h(h1c);
    const float* gp = GI1 + (32 + b)*384;  // gi1(1)
    pc0 = gp[u]; pc1 = gp[128+u]; pc2 = gp[256+u];
  }
  BARX();

  float* gout = G2 + b*128 + tid;          // dereferenced only for tid<128
  #pragma unroll 1
  for (int t = 0; t < T_; t++){
    // prefetch gi1(t+2) (consumed next iteration; hidden under matvec)
    float pn0 = 0.f, pn1 = 0.f, pn2 = 0.f;
    if (tid >= 128 && tid < 256){
      int u = tid - 128;
      int tp = (t + 2 < T_) ? t + 2 : T_ - 1;
      const float* gp = GI1 + (tp*32 + b)*384;
      pn0 = gp[u]; pn1 = gp[128+u]; pn2 = gp[256+u];
    }
    mv();   // a = WHH1@h1(t+1), c = WIH2@h1(t+1), d = WHH2@h2carry
    BARX();
    if (tid < 128){
      // GRU2: g2(t) = gru2(h1(t+1), h2carry)
      float cs0 = psBuf[384+tid]  + psBuf[1152+tid];
      float cs1 = psBuf[512+tid]  + psBuf[1280+tid];
      float cs2 = psBuf[640+tid]  + psBuf[1408+tid];
      float ds0 = psBuf[1536+tid] + psBuf[1920+tid];
      float ds1 = psBuf[1664+tid] + psBuf[2048+tid];
      float ds2 = psBuf[1792+tid] + psBuf[2176+tid];
      float r2 = fast_sigmoid(cs0 + ds0);
      float z2 = fast_sigmoid(cs1 + ds1);
      float n2 = fast_tanh(cs2 + r2*ds2);
      float g  = (1.f - z2)*n2 + z2*h2c;
      gout[t*4096] = g;                    // G2[(t*32+b)*128+tid]
      if (t > 0) h2c = g;                  // reference: h2 carry frozen at t==0
      hh2[tid] = f2h(h2c);
    } else if (tid < 256){
      // GRU1: h1(t+2) = gru1(x_{t+1}, h1(t+1))
      int u = tid - 128;
      float as0 = psBuf[u]     + psBuf[768+u];
      float as1 = psBuf[128+u] + psBuf[896+u];
      float as2 = psBuf[256+u] + psBuf[1024+u];
      float r1 = fast_sigmoid(pc0 + as0);
      float z1 = fast_sigmoid(pc1 + as1);
      float n1 = fast_tanh(pc2 + r1*as2);
      h1c = (1.f - z1)*n1 + z1*h1c;
      hh1[u] = f2h(h1c);
    }
    pc0 = pn0; pc1 = pn1; pc2 = pn2;
    BARX();
  }
}

// ---------------------------------------------------------------- K5: Kp·w_k for all G2 rows (coalesced QWt)
__launch_bounds__(128, 4)
__global__ void k_kp(const float* __restrict__ G2,
                     const float* __restrict__ QWt, const float* __restrict__ QB,
                     const float* __restrict__ MW,
                     float* __restrict__ KPWG)
{
  __shared__ __align__(16) float X[8][128];
  __shared__ float red[8][2];
  const int tid = threadIdx.x;           // c in [0,128)
  const int base = blockIdx.x * 8;       // 796 blocks x 8 rows = 6368
  for (int o = tid; o < 1024; o += 128){
    int r = o >> 7, c = o & 127;
    X[r][c] = G2[(base + r)*128 + c];
  }
  __syncthreads();
  float acc[8];
  float bias = QB[tid];
  #pragma unroll
  for (int r = 0; r < 8; r++) acc[r] = bias;
  const float4* wp = (const float4*)QWt;   // 32 groups x 128
  #pragma unroll 4
  for (int g = 0; g < 32; g++){
    float4 wv = wp[g*128 + tid];           // coalesced
    int kk = 4*g;
    #pragma unroll
    for (int r = 0; r < 8; r++){
      float4 t4 = *(const float4*)(&X[r][kk]);
      acc[r] = fmaf(t4.x, wv.x, acc[r]);
      acc[r] = fmaf(t4.y, wv.y, acc[r]);
      acc[r] = fmaf(t4.z, wv.z, acc[r]);
      acc[r] = fmaf(t4.w, wv.w, acc[r]);
    }
  }
  const float wk = MW[128 + tid];
  const int lane = tid & 63, wv_ = tid >> 6;
  #pragma unroll
  for (int r = 0; r < 8; r++){
    float pv = fast_tanh(acc[r]) * wk;
    for (int off = 32; off; off >>= 1) pv += __shfl_down(pv, off);
    if (lane == 0) red[r][wv_] = pv;
  }
  __syncthreads();
  if (tid < 8) KPWG[base + tid] = red[tid][0] + red[tid][1];
}

// ---------------------------------------------------------------- K6: predict + output
__global__ void k_pred(const int* __restrict__ question,
                       const int* __restrict__ qci, const void* __restrict__ qcm,
                       const int* __restrict__ flags,
                       const float* __restrict__ EQ, const float* __restrict__ EC,
                       const float* __restrict__ QB, const float* __restrict__ MW,
                       const float* __restrict__ G2,
                       const int* __restrict__ IDX,
                       const float* __restrict__ KPWG,
                       void* __restrict__ outp)
{
  const int blk = blockIdx.x;
  const int t = blk >> 5, b = blk & 31;
  const int tid = threadIdx.x;               // 64
  __shared__ float hist[11][132];
  __shared__ float qcs[128];
  __shared__ float og[11];
  __shared__ float kpw[11];
  __shared__ int   idxs[10];
  __shared__ float kpw0s;
  const int qid = question[b*S_ + t + 1];
  const int bflag = flags[1];
  if (tid < 10) idxs[tid] = IDX[blk*10 + tid];
  __syncthreads();
  for (int o = tid; o < 11*128; o += 64){
    int k = o >> 7, c = o & 127;
    float v;
    if (k == 0) v = G2[blk*128 + c];
    else { int s = idxs[k-1]; v = (s == 0) ? 0.f : G2[(s*32 + b)*128 + c]; }
    hist[k][c] = v;
  }
  #pragma unroll
  for (int o = tid; o < 128; o += 64){
    float v = EQ[qid*128 + o];
    #pragma unroll
    for (int q = 0; q < 4; q++){
      if (readBool(qcm, qid*4 + q, bflag))
        v += EC[qci[qid*4 + q]*128 + o];
    }
    qcs[o] = v;
  }
  {
    float pv = fast_tanh(QB[tid])      * MW[128 + tid]
             + fast_tanh(QB[tid + 64]) * MW[128 + tid + 64];
    for (int off = 32; off; off >>= 1) pv += __shfl_down(pv, off);
    if (tid == 0) kpw0s = pv;
  }
  __syncthreads();
  if (tid < 11){
    float acc = 0.f;
    for (int c = 0; c < 128; c++) acc = fmaf(qcs[c], hist[tid][c], acc);
    og[tid] = acc;
    float v;
    if (tid == 0) v = KPWG[blk];
    else { int s = idxs[tid-1]; v = (s == 0) ? kpw0s : KPWG[s*32 + b]; }
    kpw[tid] = v;
  }
  __syncthreads();
  if (tid == 0){
    float tv[11];
    #pragma unroll
    for (int k = 0; k < 11; k++){
      int valid = (k == 0) || (idxs[k-1] < t);
      tv[k] = valid ? kpw[k] : NEGV;
    }
    float m = tv[0];
    #pragma unroll
    for (int k = 1; k < 11; k++) m = fmaxf(m, tv[k]);
    float den = 0.f, num = 0.f;
    #pragma unroll
    for (int k = 0; k < 11; k++){
      float e = __expf(tv[k] - m);
      den += e;
      num = fmaf(e, og[k], num);
    }
    float p = num / den;
    int col = (t == 0) ? 0 : (t + 1);
    if (flags[0]){
      ((float*)outp)[b*S_ + col] = p;
      if (t == 0) ((float*)outp)[b*S_ + 1] = 0.f;
    } else {
      ((u16*)outp)[b*S_ + col] = f2bf(p);
      if (t == 0) ((u16*)outp)[b*S_ + 1] = (u16)0;
    }
  }
}

// ---------------------------------------------------------------- launcher
extern "C" void kernel_launch(void* const* d_in, const int* in_sizes, int n_in,
                              void* d_out, int out_size, void* d_ws, size_t ws_size,
                              hipStream_t stream)
{
  (void)in_sizes; (void)n_in; (void)out_size; (void)ws_size;
  const int* question      = (const int*)d_in[0];
  const int* response      = (const int*)d_in[1];
  const void* maskp        = d_in[2];
  const int* q_neighbors   = (const int*)d_in[3];
  const int* s_neighbors   = (const int*)d_in[4];
  const int* q_concept_idx = (const int*)d_in[5];
  const void* q_concept_mask = d_in[6];

  static const int CN[NCVT] = {2560000,256000,256,98304,49152,384,384,49152,49152,
                               384,384,49152,384,16384,128,16384,128,16384,128,
                               256,1,4096,4096};
  CvtArgs ca;
  int off = 0;
  for (int i = 0; i < NCVT; i++){
    ca.s[i] = d_in[7 + i];
    ca.nreal[i] = CN[i];
    ca.off[i] = off;
    off += (CN[i] + 3) & ~3;
  }
  ca.off[NCVT] = off;
  const int total = off;

  char* ws = (char*)d_ws;
  size_t wo = 0;
  auto alloc = [&](size_t bytes) -> void* {
    void* p = ws + wo;
    wo = (wo + bytes + 255) & ~(size_t)255;
    return p;
  };
  int*   flags = (int*)  alloc(16);
  float* CVT   = (float*)alloc((size_t)total * 4);
  float* EQREC = (float*)alloc((size_t)B_*S_*D_*4);
  float* GI1   = (float*)alloc((size_t)T_*B_*384*4);
  float* G2    = (float*)alloc((size_t)T_*B_*D_*4);
  int*   IDX   = (int*)  alloc((size_t)T_*B_*10*4);
  float* KPWG  = (float*)alloc((size_t)T_*B_*4);
  u16*   WHH1h = (u16*)  alloc(49152*2);
  u16*   WHH2h = (u16*)  alloc(49152*2);
  u16*   WIH2h = (u16*)  alloc(49152*2);
  u32*   AWt   = (u32*)  alloc(24576*4);
  u32*   ALWt  = (u32*)  alloc(8192*4);
  u32*   WIH1t = (u32*)  alloc(49152*4);
  float* QWt   = (float*)alloc(16384*4);

  const float* EQ   = CVT + ca.off[0];
  const float* EC   = CVT + ca.off[1];
  const float* ECOR = CVT + ca.off[2];
  const float* BIH1 = CVT + ca.off[5];
  const float* BHH1 = CVT + ca.off[6];
  const float* BIH2 = CVT + ca.off[9];
  const float* BHH2 = CVT + ca.off[10];
  const float* AB   = CVT + ca.off[12];
  const float* ALB  = CVT + ca.off[14];
  const float* QB   = CVT + ca.off[16];
  const float* MW   = CVT + ca.off[19];
  const float* H1I  = CVT + ca.off[21];
  const float* H2I  = CVT + ca.off[22];

  const int nCvtBlk = (total + 255)/256;
  const int TOPK_BLOCKS = (T_*B_ + 11) / 12;   // 531

  k_cvtprep<<<nCvtBlk + PREPB, 256, 0, stream>>>(
      ca, nCvtBlk,
      (const u16*)d_in[7], (const unsigned char*)maskp, flags,
      d_in[10], d_in[11], d_in[14], d_in[15], d_in[18], d_in[20], d_in[22],
      CVT, WHH1h, WHH2h, WIH2h, AWt, ALWt, WIH1t, QWt);
  k_agg<<<B_*S_/2, 256, 0, stream>>>(question, q_neighbors, s_neighbors, EQ, EC,
                                     AWt, AB, ALWt, ALB, maskp, flags, EQREC);
  k_gi1<<<dim3(T_, 4), 384, 0, stream>>>(EQREC, response, ECOR, WIH1t, BIH1, GI1);
  k_chain12<<<32 + TOPK_BLOCKS, 768, 0, stream>>>(GI1, WHH1h, BHH1, WIH2h, BIH2,
                                                  WHH2h, BHH2, H1I, H2I, G2,
                                                  question, EQ, IDX);
  k_kp<<<T_*B_/8, 128, 0, stream>>>(G2, QWt, QB, MW, KPWG);
  k_pred<<<T_*B_, 64, 0, stream>>>(question, q_concept_idx, q_concept_mask, flags,
                                   EQ, EC, QB, MW, G2, IDX, KPWG, d_out);
}